// Round 1
// baseline (2072.098 us; speedup 1.0000x reference)
//
#include <hip/hip_runtime.h>
#include <math.h>

// ---------------------------------------------------------------------------
// AtomicHAR pipeline, fp32, correctness-first.
// bs=128 seq=128 C=6 L=20 N=16384 D=64 H=256 MAL=10 Wtot=1280
// ---------------------------------------------------------------------------

#define NWIN 16384   // bs*seq
#define SEQ  128
#define BS   128
#define KSEL 3276    // int(16384*0.2)

// ---------------- encoder ----------------
// conv1: x(N,6,20) -> relu -> pool2 -> c1(N,16,10)
__global__ void k_conv1(const float* __restrict__ x, const float* __restrict__ w,
                        const float* __restrict__ b, float* __restrict__ c1) {
    int gid = blockIdx.x * blockDim.x + threadIdx.x;
    if (gid >= NWIN * 160) return;
    int n = gid / 160, r = gid % 160, oc = r / 10, t = r % 10;
    const float* xr = x + n * 120;
    float v[2];
#pragma unroll
    for (int q = 0; q < 2; ++q) {
        int p = 2 * t + q;
        float acc = b[oc];
        for (int ic = 0; ic < 6; ++ic)
#pragma unroll
            for (int dk = 0; dk < 3; ++dk) {
                int pp = p + dk - 1;
                if (pp >= 0 && pp < 20) acc += xr[ic * 20 + pp] * w[oc * 18 + ic * 3 + dk];
            }
        v[q] = acc;
    }
    c1[n * 160 + oc * 10 + t] = fmaxf(fmaxf(v[0], v[1]), 0.f);
}

// conv2: c1(N,16,10) -> relu -> pool2 -> c2(N,32,5)
__global__ void k_conv2(const float* __restrict__ c1, const float* __restrict__ w,
                        const float* __restrict__ b, float* __restrict__ c2) {
    int gid = blockIdx.x * blockDim.x + threadIdx.x;
    if (gid >= NWIN * 160) return;
    int n = gid / 160, r = gid % 160, oc = r / 5, t = r % 5;
    const float* cr = c1 + n * 160;
    float v[2];
#pragma unroll
    for (int q = 0; q < 2; ++q) {
        int p = 2 * t + q;
        float acc = b[oc];
        for (int ic = 0; ic < 16; ++ic)
#pragma unroll
            for (int dk = 0; dk < 3; ++dk) {
                int pp = p + dk - 1;
                if (pp >= 0 && pp < 10) acc += cr[ic * 10 + pp] * w[oc * 48 + ic * 3 + dk];
            }
        v[q] = acc;
    }
    c2[n * 160 + oc * 5 + t] = fmaxf(fmaxf(v[0], v[1]), 0.f);
}

// conv3: c2(N,32,5) -> relu -> pool2(VALID: len 2) -> cnn(N,64) [idx = oc*2+tp]
__global__ void k_conv3(const float* __restrict__ c2, const float* __restrict__ w,
                        const float* __restrict__ b, float* __restrict__ cnn) {
    int gid = blockIdx.x * blockDim.x + threadIdx.x;
    if (gid >= NWIN * 64) return;
    int n = gid / 64, r = gid % 64, oc = r / 2, tp = r % 2;
    const float* cr = c2 + n * 160;
    float v[2];
#pragma unroll
    for (int q = 0; q < 2; ++q) {
        int p = 2 * tp + q;
        float acc = b[oc];
        for (int ic = 0; ic < 32; ++ic)
#pragma unroll
            for (int dk = 0; dk < 3; ++dk) {
                int pp = p + dk - 1;
                if (pp >= 0 && pp < 5) acc += cr[ic * 5 + pp] * w[oc * 96 + ic * 3 + dk];
            }
        v[q] = acc;
    }
    cnn[n * 64 + oc * 2 + tp] = fmaxf(fmaxf(v[0], v[1]), 0.f);
}

// bridge: sigmoid(cnn(N,64) @ br_w(64,64) + br_b) -> bridge ws + 2 output copies
__global__ void k_bridge(const float* __restrict__ cnn, const float* __restrict__ w,
                         const float* __restrict__ b, float* __restrict__ bridge,
                         float* __restrict__ out_resh, float* __restrict__ out_fin) {
    int gid = blockIdx.x * blockDim.x + threadIdx.x;
    if (gid >= NWIN * 64) return;
    int n = gid >> 6, d = gid & 63;
    const float* cr = cnn + n * 64;
    float acc = b[d];
    for (int i = 0; i < 64; ++i) acc += cr[i] * w[i * 64 + d];
    float v = 1.f / (1.f + expf(-acc));
    bridge[gid] = v;
    out_resh[gid] = v;
    out_fin[gid] = v;
}

// f1: feat = relu(shft(N,64) @ f1_w(64,256) + f1_b)   grid: N blocks x 256
__global__ void k_f1(const float* __restrict__ bridge, const float* __restrict__ w,
                     const float* __restrict__ b, float* __restrict__ feat) {
    int n = blockIdx.x, h = threadIdx.x;
    int s = n & (SEQ - 1);
    float acc = b[h];
    if (s > 0) {
        const float* br = bridge + (n - 1) * 64;
        for (int d = 0; d < 64; ++d) acc += br[d] * w[d * 256 + h];
    }
    feat[n * 256 + h] = fmaxf(acc, 0.f);
}

// f2 + fmask + loss + scores.  grid: N blocks x 64 (one wave per row)
__global__ void k_f2_loss(const float* __restrict__ feat, const float* __restrict__ bridge,
                          const float* __restrict__ w, const float* __restrict__ b,
                          const float* __restrict__ imu_mask,
                          float* __restrict__ out_fc, float* __restrict__ out_fmask,
                          float* __restrict__ out_loss, float* __restrict__ scores) {
    int n = blockIdx.x, d = threadIdx.x;
    const float* fr = feat + n * 256;
    float acc = b[d];
    for (int h = 0; h < 256; ++h) acc += fr[h] * w[h * 64 + d];
    out_fc[n * 64 + d] = acc;
    int s = n & (SEQ - 1);
    float mval = (s == 0) ? 0.f : imu_mask[(size_t)n * 120];
    out_fmask[n * 64 + d] = mval;
    float diff = (acc - bridge[n * 64 + d]) * mval;
    float sq = diff * diff;
#pragma unroll
    for (int off = 32; off; off >>= 1) sq += __shfl_down(sq, off);
    if (d == 0) {
        float loss = sq * (1.f / 64.f);
        out_loss[n] = loss;
        scores[n] = loss * mval;
    }
}

// exact k-th largest via radix select on float bits (scores >= 0). 1 block x 256.
__global__ void k_select(const float* __restrict__ scores, float* __restrict__ cutoff) {
    __shared__ unsigned hist[256];
    __shared__ unsigned sh_prefix;
    __shared__ int sh_k;
    int tid = threadIdx.x;
    if (tid == 0) { sh_prefix = 0u; sh_k = KSEL; }
    __syncthreads();
    for (int shift = 24; shift >= 0; shift -= 8) {
        hist[tid] = 0u;
        __syncthreads();
        unsigned prefix = sh_prefix;
        unsigned pmask = (shift == 24) ? 0u : (0xFFFFFFFFu << (shift + 8));
        for (int i = tid; i < NWIN; i += 256) {
            unsigned u = __float_as_uint(scores[i]);
            if ((u & pmask) == prefix) atomicAdd(&hist[(u >> shift) & 255u], 1u);
        }
        __syncthreads();
        if (tid == 0) {
            int kk = sh_k;
            for (int bin = 255; bin >= 0; --bin) {
                int c = (int)hist[bin];
                if (kk <= c) { sh_prefix = prefix | ((unsigned)bin << shift); sh_k = kk; break; }
                kk -= c;
            }
        }
        __syncthreads();
    }
    if (tid == 0) *cutoff = __uint_as_float(sh_prefix);
}

// per-batch segmentation with gap-fill. 1 block x 128 (thread per batch).
__global__ void k_segments(const float* __restrict__ loss, const float* __restrict__ cutoff_p,
                           int* __restrict__ segs, int* __restrict__ counts) {
    int b = threadIdx.x;
    if (b >= BS) return;
    float cutoff = *cutoff_p;
    int* my = segs + b * SEQ;
    int cnt = 0, prev = 0;
    bool has = false;
    for (int s = 0; s < SEQ; ++s) {
        if (loss[b * SEQ + s] > cutoff) {
            if (has) {
                if (s - prev > 10) {
                    my[cnt++] = prev;
                    int cur = prev;
                    while (cur < s) {
                        cur += 10;
                        if (cur >= s) break;
                        my[cnt++] = cur;
                    }
                } else {
                    my[cnt++] = prev;
                }
            }
            has = true; prev = s;
        }
    }
    if (has) my[cnt++] = prev;
    counts[b] = cnt;
}

// prefix-scan counts, emit (b,last,e) records. 1 block x 128.
__global__ void k_emit(const int* __restrict__ counts, const int* __restrict__ segs,
                       int* __restrict__ rec_b, int* __restrict__ rec_last,
                       int* __restrict__ rec_e, int* __restrict__ total_out) {
    __shared__ int offs[BS + 1];
    int tid = threadIdx.x;
    if (tid == 0) {
        int acc = 0;
        for (int b = 0; b < BS; ++b) { offs[b] = acc; acc += counts[b]; }
        offs[BS] = acc;
        *total_out = acc;
        if (acc == 0) { rec_b[0] = 0; rec_last[0] = 0; rec_e[0] = 0; }  // fallback dummy
    }
    __syncthreads();
    int b = tid;
    int o = offs[b], c = counts[b];
    for (int j = 0; j < c; ++j) {
        int idx = o + j;
        if (idx >= NWIN) break;
        rec_b[idx] = b;
        rec_last[idx] = (j > 0) ? segs[b * SEQ + j - 1] : 0;
        rec_e[idx] = segs[b * SEQ + j];
    }
}

// atom_features: af[a, d(64), r(10)] = (src>=last) ? bridge[b,src,d] : 0, src = e-10+r
__global__ void k_gather_feats(const int* __restrict__ rec_b, const int* __restrict__ rec_last,
                               const int* __restrict__ rec_e, const float* __restrict__ bridge,
                               float* __restrict__ af, int A) {
    int gid = blockIdx.x * blockDim.x + threadIdx.x;
    if (gid >= A * 640) return;
    int a = gid / 640, rem = gid % 640, d = rem / 10, r = rem % 10;
    int b = rec_b[a], last = rec_last[a], e = rec_e[a];
    int src = e - 10 + r;
    float v = 0.f;
    if (src >= last) v = bridge[(b * SEQ + src) * 64 + d];
    af[gid] = v;
}

// imu_atoms + mask: (A, 6, 1280)
__global__ void k_gather_atoms(const int* __restrict__ rec_b, const int* __restrict__ rec_last,
                               const int* __restrict__ rec_e, const float* __restrict__ x,
                               float* __restrict__ out_atoms, float* __restrict__ out_mask, int A) {
    int gid = blockIdx.x * blockDim.x + threadIdx.x;
    if (gid >= A * 7680) return;
    int a = gid / 7680, rem = gid % 7680, c = rem / 1280, wcol = rem % 1280;
    int b = rec_b[a], last = rec_last[a], e = rec_e[a];
    int W = (e - last) * 20;
    int sc = wcol - (1280 - W);
    float v = 0.f, m = 0.f;
    if (sc >= 0 && sc < W) {
        int t = sc / 20, l = sc % 20;
        v = x[((b * SEQ + last + t) * 6 + c) * 20 + l];
        m = 1.f;
    }
    out_atoms[gid] = v;
    out_mask[gid] = m;
}

// autoencoder per segment: af(64,10) -> conv/pool/conv -> emb(32) -> hd(256). grid A x 64
__global__ void k_ae(const float* __restrict__ af,
                     const float* __restrict__ ae1w, const float* __restrict__ ae1b,
                     const float* __restrict__ ae2w, const float* __restrict__ ae2b,
                     const float* __restrict__ ae3w, const float* __restrict__ ae3b,
                     const float* __restrict__ ad1w, const float* __restrict__ ad1b,
                     float* __restrict__ hd) {
    __shared__ float af_s[640];
    __shared__ float c1s[320];
    __shared__ float h2s[80];
    __shared__ float embs[32];
    int a = blockIdx.x, tid = threadIdx.x;
    const float* afr = af + a * 640;
    for (int i = tid; i < 640; i += 64) af_s[i] = afr[i];
    __syncthreads();
    for (int idx = tid; idx < 320; idx += 64) {
        int o = idx / 10, p = idx % 10;
        float acc = ae1b[o];
        for (int ic = 0; ic < 64; ++ic) {
            const float* wr = ae1w + o * 192 + ic * 3;
            const float* ar = af_s + ic * 10;
#pragma unroll
            for (int dk = 0; dk < 3; ++dk) {
                int pp = p + dk - 1;
                if (pp >= 0 && pp < 10) acc += ar[pp] * wr[dk];
            }
        }
        c1s[o * 10 + p] = fmaxf(acc, 0.f);
    }
    __syncthreads();
    for (int idx = tid; idx < 80; idx += 64) {
        int c = idx / 5, t = idx % 5;
        float acc = ae2b[c];
        for (int ic = 0; ic < 32; ++ic) {
#pragma unroll
            for (int dk = 0; dk < 3; ++dk) {
                int tt = t + dk - 1;
                if (tt >= 0 && tt < 5) {
                    float m = fmaxf(c1s[ic * 10 + 2 * tt], c1s[ic * 10 + 2 * tt + 1]);
                    acc += m * ae2w[c * 96 + ic * 3 + dk];
                }
            }
        }
        h2s[c * 5 + t] = fmaxf(acc, 0.f);
    }
    __syncthreads();
    if (tid < 32) {
        float acc = ae3b[tid];
        for (int i = 0; i < 80; ++i) acc += h2s[i] * ae3w[i * 32 + tid];
        embs[tid] = acc;   // no relu on emb
    }
    __syncthreads();
    for (int idx = tid; idx < 256; idx += 64) {
        float acc = ad1b[idx];
#pragma unroll
        for (int o = 0; o < 32; ++o) acc += embs[o] * ad1w[o * 256 + idx];
        hd[a * 256 + idx] = fmaxf(acc, 0.f);
    }
}

// atom_gen = hd(A,256) @ ad2_w(256,7680) + ad2_b.  block: 256 thr = 64 j x 4 q, 32 a-tile
__global__ __launch_bounds__(256) void k_ad2(const float* __restrict__ hd,
                                             const float* __restrict__ w,
                                             const float* __restrict__ bias,
                                             float* __restrict__ out, int A) {
    __shared__ float hs[32][256];
    int j = blockIdx.x * 64 + (threadIdx.x & 63);
    int q = threadIdx.x >> 6;
    int a0 = blockIdx.y * 32;
    for (int idx = threadIdx.x; idx < 32 * 256; idx += 256) {
        int row = idx >> 8, col = idx & 255;
        hs[row][col] = (a0 + row < A) ? hd[(a0 + row) * 256 + col] : 0.f;
    }
    __syncthreads();
    float acc[8] = {0.f, 0.f, 0.f, 0.f, 0.f, 0.f, 0.f, 0.f};
    for (int k = 0; k < 256; ++k) {
        float wv = w[k * 7680 + j];
#pragma unroll
        for (int i = 0; i < 8; ++i) acc[i] += hs[q + i * 4][k] * wv;
    }
    float bb = bias[j];
#pragma unroll
    for (int i = 0; i < 8; ++i) {
        int a = a0 + q + i * 4;
        if (a < A) out[(size_t)a * 7680 + j] = acc[i] + bb;
    }
}

// decoder: bridge_resh einsum d1_w -> relu -> conv d2 -> imu_gen. grid N x 64
__global__ void k_decoder(const float* __restrict__ bridge,
                          const float* __restrict__ d1w, const float* __restrict__ d1b,
                          const float* __restrict__ d2w, const float* __restrict__ d2b,
                          float* __restrict__ out) {
    __shared__ float br[64];
    __shared__ float g[640];
    int n = blockIdx.x, tid = threadIdx.x;
    br[tid] = bridge[n * 64 + tid];
    __syncthreads();
    for (int idx = tid; idx < 640; idx += 64) {
        int o = idx / 20, p = idx % 20, i = p / 5, kk = p % 5;
        float acc = d1b[o];
#pragma unroll
        for (int c = 0; c < 16; ++c) acc += br[c * 4 + i] * d1w[c * 160 + o * 5 + kk];
        g[o * 20 + p] = fmaxf(acc, 0.f);
    }
    __syncthreads();
    for (int idx = tid; idx < 120; idx += 64) {
        int oc = idx / 20, t = idx % 20;
        float acc = d2b[oc];
        for (int ic = 0; ic < 32; ++ic) {
            const float* gr = g + ic * 20;
            const float* wr = d2w + oc * 96 + ic * 3;
#pragma unroll
            for (int dk = 0; dk < 3; ++dk) {
                int tt = t + dk - 1;
                if (tt >= 0 && tt < 20) acc += gr[tt] * wr[dk];
            }
        }
        out[(size_t)n * 120 + idx] = acc;
    }
}

// ---------------------------------------------------------------------------
extern "C" void kernel_launch(void* const* d_in, const int* in_sizes, int n_in,
                              void* d_out, int out_size, void* d_ws, size_t ws_size,
                              hipStream_t stream) {
    const float* x        = (const float*)d_in[0];
    const float* imu_mask = (const float*)d_in[1];
    // d_in[2] = imu_len (unused by reference)
    const float* c1_w = (const float*)d_in[3];
    const float* c1_b = (const float*)d_in[4];
    const float* c2_w = (const float*)d_in[5];
    const float* c2_b = (const float*)d_in[6];
    const float* c3_w = (const float*)d_in[7];
    const float* c3_b = (const float*)d_in[8];
    const float* br_w = (const float*)d_in[9];
    const float* br_b = (const float*)d_in[10];
    const float* f1_w = (const float*)d_in[11];
    const float* f1_b = (const float*)d_in[12];
    const float* f2_w = (const float*)d_in[13];
    const float* f2_b = (const float*)d_in[14];
    const float* d1_w = (const float*)d_in[15];
    const float* d1_b = (const float*)d_in[16];
    const float* d2_w = (const float*)d_in[17];
    const float* d2_b = (const float*)d_in[18];
    const float* ae1_w = (const float*)d_in[19];
    const float* ae1_b = (const float*)d_in[20];
    const float* ae2_w = (const float*)d_in[21];
    const float* ae2_b = (const float*)d_in[22];
    const float* ae3_w = (const float*)d_in[23];
    const float* ae3_b = (const float*)d_in[24];
    const float* ad1_w = (const float*)d_in[25];
    const float* ad1_b = (const float*)d_in[26];
    const float* ad2_w = (const float*)d_in[27];
    const float* ad2_b = (const float*)d_in[28];

    // A from out_size: out_size = 6,176,768 + 23,040*A
    int A = (out_size - 6176768) / 23040;
    if (A < 1) A = 1;

    float* out = (float*)d_out;
    size_t o_imu_gen  = 0;
    size_t o_atom_gen = 1966080;
    size_t o_mask     = o_atom_gen + (size_t)A * 7680;
    size_t o_atoms    = o_mask + (size_t)A * 7680;
    size_t o_resh     = o_atoms + (size_t)A * 7680;
    size_t o_fin      = o_resh + 1048576;
    size_t o_fc       = o_fin + 1048576;
    size_t o_fmask    = o_fc + 1048576;
    size_t o_loss     = o_fmask + 1048576;

    // workspace layout (float units)
    float* wsf = (float*)d_ws;
    int*   wsi = (int*)d_ws;
    const size_t W_BRIDGE = 0;                       // 1,048,576
    const size_t W_C1     = 1048576;                 // 2,621,440 (af overlays here later)
    const size_t W_C2     = W_C1 + 2621440;          // 3,670,016
    const size_t W_CNN    = W_C2 + 2621440;          // 6,291,456
    const size_t W_FEAT   = W_CNN + 1048576;         // 7,340,032
    const size_t W_SCORES = W_FEAT + 4194304;        // 11,534,336
    const size_t W_CUTOFF = W_SCORES + 16384;        // 11,550,720
    const size_t MW       = W_CUTOFF + 64;           // meta (int units)
    int* counts   = wsi + MW;
    int* total    = wsi + MW + 128;
    int* segs     = wsi + MW + 192;
    int* rec_b    = wsi + MW + 192 + 16384;
    int* rec_last = rec_b + 16384;
    int* rec_e    = rec_last + 16384;
    float* hd     = wsf + MW + 192 + 16384 * 4;      // A*256 floats
    const size_t W_AF = W_C1;                        // overlay: A*640 <= 10,485,760

    // zero segment records so a device/host A mismatch stays deterministic
    hipMemsetAsync(rec_b, 0, 3 * 16384 * sizeof(int), stream);

    const int T = 256;
    k_conv1<<<(NWIN * 160 + T - 1) / T, T, 0, stream>>>(x, c1_w, c1_b, wsf + W_C1);
    k_conv2<<<(NWIN * 160 + T - 1) / T, T, 0, stream>>>(wsf + W_C1, c2_w, c2_b, wsf + W_C2);
    k_conv3<<<(NWIN * 64 + T - 1) / T, T, 0, stream>>>(wsf + W_C2, c3_w, c3_b, wsf + W_CNN);
    k_bridge<<<(NWIN * 64 + T - 1) / T, T, 0, stream>>>(wsf + W_CNN, br_w, br_b,
                                                        wsf + W_BRIDGE, out + o_resh, out + o_fin);
    k_f1<<<NWIN, 256, 0, stream>>>(wsf + W_BRIDGE, f1_w, f1_b, wsf + W_FEAT);
    k_f2_loss<<<NWIN, 64, 0, stream>>>(wsf + W_FEAT, wsf + W_BRIDGE, f2_w, f2_b, imu_mask,
                                       out + o_fc, out + o_fmask, out + o_loss, wsf + W_SCORES);
    k_select<<<1, 256, 0, stream>>>(wsf + W_SCORES, wsf + W_CUTOFF);
    k_segments<<<1, 128, 0, stream>>>(out + o_loss, wsf + W_CUTOFF, segs, counts);
    k_emit<<<1, 128, 0, stream>>>(counts, segs, rec_b, rec_last, rec_e, total);
    k_gather_feats<<<(A * 640 + T - 1) / T, T, 0, stream>>>(rec_b, rec_last, rec_e,
                                                            wsf + W_BRIDGE, wsf + W_AF, A);
    k_gather_atoms<<<(A * 7680 + T - 1) / T, T, 0, stream>>>(rec_b, rec_last, rec_e, x,
                                                             out + o_atoms, out + o_mask, A);
    k_ae<<<A, 64, 0, stream>>>(wsf + W_AF, ae1_w, ae1_b, ae2_w, ae2_b, ae3_w, ae3_b,
                               ad1_w, ad1_b, hd);
    dim3 g2(7680 / 64, (A + 31) / 32);
    k_ad2<<<g2, 256, 0, stream>>>(hd, ad2_w, ad2_b, out + o_atom_gen, A);
    k_decoder<<<NWIN, 64, 0, stream>>>(wsf + W_BRIDGE, d1_w, d1_b, d2_w, d2_b, out + o_imu_gen);
}

// Round 2
// 1921.676 us; speedup vs baseline: 1.0783x; 1.0783x over previous
//
#include <hip/hip_runtime.h>
#include <math.h>

// ---------------------------------------------------------------------------
// AtomicHAR pipeline, fp32.
// bs=128 seq=128 C=6 L=20 N=16384 D=64 H=256 MAL=10 Wtot=1280
// ---------------------------------------------------------------------------

#define NWIN 16384   // bs*seq
#define SEQ  128
#define BS   128
#define KSEL 3276    // int(16384*0.2)
#define SEGSTRIDE 160    // worst-case segments per batch ~140
#define RECCAP 18432     // worst-case total segments

// ---------------- encoder ----------------
__global__ void k_conv1(const float* __restrict__ x, const float* __restrict__ w,
                        const float* __restrict__ b, float* __restrict__ c1) {
    int gid = blockIdx.x * blockDim.x + threadIdx.x;
    if (gid >= NWIN * 160) return;
    int n = gid / 160, r = gid % 160, oc = r / 10, t = r % 10;
    const float* xr = x + n * 120;
    float v[2];
#pragma unroll
    for (int q = 0; q < 2; ++q) {
        int p = 2 * t + q;
        float acc = b[oc];
        for (int ic = 0; ic < 6; ++ic)
#pragma unroll
            for (int dk = 0; dk < 3; ++dk) {
                int pp = p + dk - 1;
                if (pp >= 0 && pp < 20) acc += xr[ic * 20 + pp] * w[oc * 18 + ic * 3 + dk];
            }
        v[q] = acc;
    }
    c1[n * 160 + oc * 10 + t] = fmaxf(fmaxf(v[0], v[1]), 0.f);
}

__global__ void k_conv2(const float* __restrict__ c1, const float* __restrict__ w,
                        const float* __restrict__ b, float* __restrict__ c2) {
    int gid = blockIdx.x * blockDim.x + threadIdx.x;
    if (gid >= NWIN * 160) return;
    int n = gid / 160, r = gid % 160, oc = r / 5, t = r % 5;
    const float* cr = c1 + n * 160;
    float v[2];
#pragma unroll
    for (int q = 0; q < 2; ++q) {
        int p = 2 * t + q;
        float acc = b[oc];
        for (int ic = 0; ic < 16; ++ic)
#pragma unroll
            for (int dk = 0; dk < 3; ++dk) {
                int pp = p + dk - 1;
                if (pp >= 0 && pp < 10) acc += cr[ic * 10 + pp] * w[oc * 48 + ic * 3 + dk];
            }
        v[q] = acc;
    }
    c2[n * 160 + oc * 5 + t] = fmaxf(fmaxf(v[0], v[1]), 0.f);
}

__global__ void k_conv3(const float* __restrict__ c2, const float* __restrict__ w,
                        const float* __restrict__ b, float* __restrict__ cnn) {
    int gid = blockIdx.x * blockDim.x + threadIdx.x;
    if (gid >= NWIN * 64) return;
    int n = gid / 64, r = gid % 64, oc = r / 2, tp = r % 2;
    const float* cr = c2 + n * 160;
    float v[2];
#pragma unroll
    for (int q = 0; q < 2; ++q) {
        int p = 2 * tp + q;
        float acc = b[oc];
        for (int ic = 0; ic < 32; ++ic)
#pragma unroll
            for (int dk = 0; dk < 3; ++dk) {
                int pp = p + dk - 1;
                if (pp >= 0 && pp < 5) acc += cr[ic * 5 + pp] * w[oc * 96 + ic * 3 + dk];
            }
        v[q] = acc;
    }
    cnn[n * 64 + oc * 2 + tp] = fmaxf(fmaxf(v[0], v[1]), 0.f);
}

__global__ void k_bridge(const float* __restrict__ cnn, const float* __restrict__ w,
                         const float* __restrict__ b, float* __restrict__ bridge,
                         float* __restrict__ out_resh, float* __restrict__ out_fin) {
    int gid = blockIdx.x * blockDim.x + threadIdx.x;
    if (gid >= NWIN * 64) return;
    int n = gid >> 6, d = gid & 63;
    const float* cr = cnn + n * 64;
    float acc = b[d];
    for (int i = 0; i < 64; ++i) acc += cr[i] * w[i * 64 + d];
    float v = 1.f / (1.f + expf(-acc));
    bridge[gid] = v;
    out_resh[gid] = v;
    out_fin[gid] = v;
}

__global__ void k_f1(const float* __restrict__ bridge, const float* __restrict__ w,
                     const float* __restrict__ b, float* __restrict__ feat) {
    int n = blockIdx.x, h = threadIdx.x;
    int s = n & (SEQ - 1);
    float acc = b[h];
    if (s > 0) {
        const float* br = bridge + (n - 1) * 64;
        for (int d = 0; d < 64; ++d) acc += br[d] * w[d * 256 + h];
    }
    feat[n * 256 + h] = fmaxf(acc, 0.f);
}

__global__ void k_f2_loss(const float* __restrict__ feat, const float* __restrict__ bridge,
                          const float* __restrict__ w, const float* __restrict__ b,
                          const float* __restrict__ imu_mask,
                          float* __restrict__ out_fc, float* __restrict__ out_fmask,
                          float* __restrict__ out_loss, float* __restrict__ scores) {
    int n = blockIdx.x, d = threadIdx.x;
    const float* fr = feat + n * 256;
    float acc = b[d];
    for (int h = 0; h < 256; ++h) acc += fr[h] * w[h * 64 + d];
    out_fc[n * 64 + d] = acc;
    int s = n & (SEQ - 1);
    float mval = (s == 0) ? 0.f : imu_mask[(size_t)n * 120];
    out_fmask[n * 64 + d] = mval;
    float diff = (acc - bridge[n * 64 + d]) * mval;
    float sq = diff * diff;
#pragma unroll
    for (int off = 32; off; off >>= 1) sq += __shfl_down(sq, off);
    if (d == 0) {
        float loss = sq * (1.f / 64.f);
        out_loss[n] = loss;
        scores[n] = loss * mval;
    }
}

// exact k-th largest via radix select on float bits (scores >= 0). 1 block x 256.
__global__ void k_select(const float* __restrict__ scores, float* __restrict__ cutoff) {
    __shared__ unsigned hist[256];
    __shared__ unsigned sh_prefix;
    __shared__ int sh_k;
    int tid = threadIdx.x;
    if (tid == 0) { sh_prefix = 0u; sh_k = KSEL; }
    __syncthreads();
    for (int shift = 24; shift >= 0; shift -= 8) {
        hist[tid] = 0u;
        __syncthreads();
        unsigned prefix = sh_prefix;
        unsigned pmask = (shift == 24) ? 0u : (0xFFFFFFFFu << (shift + 8));
        for (int i = tid; i < NWIN; i += 256) {
            unsigned u = __float_as_uint(scores[i]);
            if ((u & pmask) == prefix) atomicAdd(&hist[(u >> shift) & 255u], 1u);
        }
        __syncthreads();
        if (tid == 0) {
            int kk = sh_k;
            for (int bin = 255; bin >= 0; --bin) {
                int c = (int)hist[bin];
                if (kk <= c) { sh_prefix = prefix | ((unsigned)bin << shift); sh_k = kk; break; }
                kk -= c;
            }
        }
        __syncthreads();
    }
    if (tid == 0) *cutoff = __uint_as_float(sh_prefix);
}

// per-batch segmentation with gap-fill. 1 block x 128 (thread per batch).
__global__ void k_segments(const float* __restrict__ loss, const float* __restrict__ cutoff_p,
                           int* __restrict__ segs, int* __restrict__ counts) {
    int b = threadIdx.x;
    if (b >= BS) return;
    float cutoff = *cutoff_p;
    int* my = segs + b * SEGSTRIDE;
    int cnt = 0, prev = 0;
    bool has = false;
    for (int s = 0; s < SEQ; ++s) {
        if (loss[b * SEQ + s] > cutoff) {
            if (has) {
                if (s - prev > 10) {
                    my[cnt++] = prev;
                    int cur = prev;
                    while (cur < s) {
                        cur += 10;
                        if (cur >= s) break;
                        my[cnt++] = cur;
                    }
                } else {
                    my[cnt++] = prev;
                }
            }
            has = true; prev = s;
        }
    }
    if (has) my[cnt++] = prev;
    counts[b] = cnt;
}

// prefix-scan counts, emit (b,last,e) records. 1 block x 128.
__global__ void k_emit(const int* __restrict__ counts, const int* __restrict__ segs,
                       int* __restrict__ rec_b, int* __restrict__ rec_last,
                       int* __restrict__ rec_e, int* __restrict__ total_out) {
    __shared__ int offs[BS + 1];
    int tid = threadIdx.x;
    if (tid == 0) {
        int acc = 0;
        for (int b = 0; b < BS; ++b) { offs[b] = acc; acc += counts[b]; }
        offs[BS] = acc;
        *total_out = acc;
        if (acc == 0) { rec_b[0] = 0; rec_last[0] = 0; rec_e[0] = 0; }  // fallback dummy
    }
    __syncthreads();
    int b = tid;
    int o = offs[b], c = counts[b];
    for (int j = 0; j < c; ++j) {
        int idx = o + j;
        if (idx >= RECCAP) break;
        rec_b[idx] = b;
        rec_last[idx] = (j > 0) ? segs[b * SEGSTRIDE + j - 1] : 0;
        rec_e[idx] = segs[b * SEGSTRIDE + j];
    }
}

// imu_atoms + mask: (A, 6, 1280)
__global__ void k_gather_atoms(const int* __restrict__ rec_b, const int* __restrict__ rec_last,
                               const int* __restrict__ rec_e, const float* __restrict__ x,
                               float* __restrict__ out_atoms, float* __restrict__ out_mask, int A) {
    int gid = blockIdx.x * blockDim.x + threadIdx.x;
    if (gid >= A * 7680) return;
    int a = gid / 7680, rem = gid % 7680, c = rem / 1280, wcol = rem % 1280;
    int b = rec_b[a], last = rec_last[a], e = rec_e[a];
    int W = (e - last) * 20;
    int sc = wcol - (1280 - W);
    float v = 0.f, m = 0.f;
    if (sc >= 0 && sc < W) {
        int t = sc / 20, l = sc % 20;
        v = x[((b * SEQ + last + t) * 6 + c) * 20 + l];
        m = 1.f;
    }
    out_atoms[gid] = v;
    out_mask[gid] = m;
}

// autoencoder per segment: gather af(64,10) from bridge -> conv/pool/conv -> emb(32) -> hd(256)
__global__ void k_ae(const int* __restrict__ rec_b, const int* __restrict__ rec_last,
                     const int* __restrict__ rec_e, const float* __restrict__ bridge,
                     const float* __restrict__ ae1w, const float* __restrict__ ae1b,
                     const float* __restrict__ ae2w, const float* __restrict__ ae2b,
                     const float* __restrict__ ae3w, const float* __restrict__ ae3b,
                     const float* __restrict__ ad1w, const float* __restrict__ ad1b,
                     float* __restrict__ hd) {
    __shared__ float af_s[640];
    __shared__ float c1s[320];
    __shared__ float h2s[80];
    __shared__ float embs[32];
    int a = blockIdx.x, tid = threadIdx.x;
    int b = rec_b[a], last = rec_last[a], e = rec_e[a];
    for (int i = tid; i < 640; i += 64) {
        int d = i / 10, r = i % 10;
        int src = e - 10 + r;
        af_s[i] = (src >= last) ? bridge[(b * SEQ + src) * 64 + d] : 0.f;
    }
    __syncthreads();
    for (int idx = tid; idx < 320; idx += 64) {
        int o = idx / 10, p = idx % 10;
        float acc = ae1b[o];
        for (int ic = 0; ic < 64; ++ic) {
            const float* wr = ae1w + o * 192 + ic * 3;
            const float* ar = af_s + ic * 10;
#pragma unroll
            for (int dk = 0; dk < 3; ++dk) {
                int pp = p + dk - 1;
                if (pp >= 0 && pp < 10) acc += ar[pp] * wr[dk];
            }
        }
        c1s[o * 10 + p] = fmaxf(acc, 0.f);
    }
    __syncthreads();
    for (int idx = tid; idx < 80; idx += 64) {
        int c = idx / 5, t = idx % 5;
        float acc = ae2b[c];
        for (int ic = 0; ic < 32; ++ic) {
#pragma unroll
            for (int dk = 0; dk < 3; ++dk) {
                int tt = t + dk - 1;
                if (tt >= 0 && tt < 5) {
                    float m = fmaxf(c1s[ic * 10 + 2 * tt], c1s[ic * 10 + 2 * tt + 1]);
                    acc += m * ae2w[c * 96 + ic * 3 + dk];
                }
            }
        }
        h2s[c * 5 + t] = fmaxf(acc, 0.f);
    }
    __syncthreads();
    if (tid < 32) {
        float acc = ae3b[tid];
        for (int i = 0; i < 80; ++i) acc += h2s[i] * ae3w[i * 32 + tid];
        embs[tid] = acc;   // no relu on emb
    }
    __syncthreads();
    for (int idx = tid; idx < 256; idx += 64) {
        float acc = ad1b[idx];
#pragma unroll
        for (int o = 0; o < 32; ++o) acc += embs[o] * ad1w[o * 256 + idx];
        hd[a * 256 + idx] = fmaxf(acc, 0.f);
    }
}

// atom_gen = hd(A,256) @ ad2_w(256,7680) + ad2_b.
// block 256 thr: 64 j-quads x 4 q; each thread: 8 a-rows x 4 j-cols.
// grid: (ceil(A/32), 30)  -- x = a-tile so consecutive blocks share the j-slab (L2)
__global__ __launch_bounds__(256) void k_ad2(const float* __restrict__ hd,
                                             const float* __restrict__ w,
                                             const float* __restrict__ bias,
                                             float* __restrict__ out, int A) {
    __shared__ float hs[32][256];
    int jq = threadIdx.x & 63;          // 0..63
    int q  = threadIdx.x >> 6;          // 0..3
    int jw = blockIdx.y * 64 + jq;      // float4 index into a row of w
    int j0 = jw * 4;
    int a0 = blockIdx.x * 32;
    for (int idx = threadIdx.x; idx < 32 * 256; idx += 256) {
        int row = idx >> 8, col = idx & 255;
        hs[row][col] = (a0 + row < A) ? hd[(a0 + row) * 256 + col] : 0.f;
    }
    __syncthreads();
    float acc[8][4] = {};
    const float4* w4 = (const float4*)w;
    for (int k = 0; k < 256; k += 4) {
        float4 wv0 = w4[(size_t)(k + 0) * 1920 + jw];
        float4 wv1 = w4[(size_t)(k + 1) * 1920 + jw];
        float4 wv2 = w4[(size_t)(k + 2) * 1920 + jw];
        float4 wv3 = w4[(size_t)(k + 3) * 1920 + jw];
#pragma unroll
        for (int i = 0; i < 8; ++i) {
            float4 h4 = *(const float4*)&hs[q + i * 4][k];
            acc[i][0] += h4.x * wv0.x + h4.y * wv1.x + h4.z * wv2.x + h4.w * wv3.x;
            acc[i][1] += h4.x * wv0.y + h4.y * wv1.y + h4.z * wv2.y + h4.w * wv3.y;
            acc[i][2] += h4.x * wv0.z + h4.y * wv1.z + h4.z * wv2.z + h4.w * wv3.z;
            acc[i][3] += h4.x * wv0.w + h4.y * wv1.w + h4.z * wv2.w + h4.w * wv3.w;
        }
    }
    float4 bb = ((const float4*)bias)[jw];
#pragma unroll
    for (int i = 0; i < 8; ++i) {
        int a = a0 + q + i * 4;
        if (a < A) {
            float4 r;
            r.x = acc[i][0] + bb.x;
            r.y = acc[i][1] + bb.y;
            r.z = acc[i][2] + bb.z;
            r.w = acc[i][3] + bb.w;
            *(float4*)&out[(size_t)a * 7680 + j0] = r;
        }
    }
}

// decoder: bridge_resh einsum d1_w -> relu -> conv d2 -> imu_gen. grid N x 64
__global__ void k_decoder(const float* __restrict__ bridge,
                          const float* __restrict__ d1w, const float* __restrict__ d1b,
                          const float* __restrict__ d2w, const float* __restrict__ d2b,
                          float* __restrict__ out) {
    __shared__ float br[64];
    __shared__ float g[640];
    int n = blockIdx.x, tid = threadIdx.x;
    br[tid] = bridge[n * 64 + tid];
    __syncthreads();
    for (int idx = tid; idx < 640; idx += 64) {
        int o = idx / 20, p = idx % 20, i = p / 5, kk = p % 5;
        float acc = d1b[o];
#pragma unroll
        for (int c = 0; c < 16; ++c) acc += br[c * 4 + i] * d1w[c * 160 + o * 5 + kk];
        g[o * 20 + p] = fmaxf(acc, 0.f);
    }
    __syncthreads();
    for (int idx = tid; idx < 120; idx += 64) {
        int oc = idx / 20, t = idx % 20;
        float acc = d2b[oc];
        for (int ic = 0; ic < 32; ++ic) {
            const float* gr = g + ic * 20;
            const float* wr = d2w + oc * 96 + ic * 3;
#pragma unroll
            for (int dk = 0; dk < 3; ++dk) {
                int tt = t + dk - 1;
                if (tt >= 0 && tt < 20) acc += gr[tt] * wr[dk];
            }
        }
        out[(size_t)n * 120 + idx] = acc;
    }
}

// ---------------------------------------------------------------------------
extern "C" void kernel_launch(void* const* d_in, const int* in_sizes, int n_in,
                              void* d_out, int out_size, void* d_ws, size_t ws_size,
                              hipStream_t stream) {
    const float* x        = (const float*)d_in[0];
    const float* imu_mask = (const float*)d_in[1];
    const float* c1_w = (const float*)d_in[3];
    const float* c1_b = (const float*)d_in[4];
    const float* c2_w = (const float*)d_in[5];
    const float* c2_b = (const float*)d_in[6];
    const float* c3_w = (const float*)d_in[7];
    const float* c3_b = (const float*)d_in[8];
    const float* br_w = (const float*)d_in[9];
    const float* br_b = (const float*)d_in[10];
    const float* f1_w = (const float*)d_in[11];
    const float* f1_b = (const float*)d_in[12];
    const float* f2_w = (const float*)d_in[13];
    const float* f2_b = (const float*)d_in[14];
    const float* d1_w = (const float*)d_in[15];
    const float* d1_b = (const float*)d_in[16];
    const float* d2_w = (const float*)d_in[17];
    const float* d2_b = (const float*)d_in[18];
    const float* ae1_w = (const float*)d_in[19];
    const float* ae1_b = (const float*)d_in[20];
    const float* ae2_w = (const float*)d_in[21];
    const float* ae2_b = (const float*)d_in[22];
    const float* ae3_w = (const float*)d_in[23];
    const float* ae3_b = (const float*)d_in[24];
    const float* ad1_w = (const float*)d_in[25];
    const float* ad1_b = (const float*)d_in[26];
    const float* ad2_w = (const float*)d_in[27];
    const float* ad2_b = (const float*)d_in[28];

    // A from out_size: out_size = 6,176,768 + 23,040*A
    int A = (out_size - 6176768) / 23040;
    if (A < 1) A = 1;

    float* out = (float*)d_out;
    size_t o_imu_gen  = 0;
    size_t o_atom_gen = 1966080;
    size_t o_mask     = o_atom_gen + (size_t)A * 7680;
    size_t o_atoms    = o_mask + (size_t)A * 7680;
    size_t o_resh     = o_atoms + (size_t)A * 7680;
    size_t o_fin      = o_resh + 1048576;
    size_t o_fc       = o_fin + 1048576;
    size_t o_fmask    = o_fc + 1048576;
    size_t o_loss     = o_fmask + 1048576;

    // workspace layout (float units)
    float* wsf = (float*)d_ws;
    int*   wsi = (int*)d_ws;
    const size_t W_BRIDGE = 0;                       // 1,048,576
    const size_t W_C1     = 1048576;                 // 2,621,440
    const size_t W_C2     = W_C1 + 2621440;          // 2,621,440
    const size_t W_CNN    = W_C2 + 2621440;          // 1,048,576
    const size_t W_FEAT   = W_CNN + 1048576;         // 4,194,304
    const size_t W_SCORES = W_FEAT + 4194304;        // 16,384
    const size_t W_CUTOFF = W_SCORES + 16384;        // 64
    const size_t MW       = W_CUTOFF + 64;           // meta (int units)
    int* counts   = wsi + MW;
    int* total    = wsi + MW + 128;
    int* segs     = wsi + MW + 192;                          // BS*SEGSTRIDE = 20480
    int* rec_b    = wsi + MW + 192 + BS * SEGSTRIDE;
    int* rec_last = rec_b + RECCAP;
    int* rec_e    = rec_last + RECCAP;
    float* hd     = wsf + MW + 192 + BS * SEGSTRIDE + 3 * RECCAP;  // A*256 floats

    hipMemsetAsync(rec_b, 0, 3 * RECCAP * sizeof(int), stream);

    const int T = 256;
    k_conv1<<<(NWIN * 160 + T - 1) / T, T, 0, stream>>>(x, c1_w, c1_b, wsf + W_C1);
    k_conv2<<<(NWIN * 160 + T - 1) / T, T, 0, stream>>>(wsf + W_C1, c2_w, c2_b, wsf + W_C2);
    k_conv3<<<(NWIN * 64 + T - 1) / T, T, 0, stream>>>(wsf + W_C2, c3_w, c3_b, wsf + W_CNN);
    k_bridge<<<(NWIN * 64 + T - 1) / T, T, 0, stream>>>(wsf + W_CNN, br_w, br_b,
                                                        wsf + W_BRIDGE, out + o_resh, out + o_fin);
    k_f1<<<NWIN, 256, 0, stream>>>(wsf + W_BRIDGE, f1_w, f1_b, wsf + W_FEAT);
    k_f2_loss<<<NWIN, 64, 0, stream>>>(wsf + W_FEAT, wsf + W_BRIDGE, f2_w, f2_b, imu_mask,
                                       out + o_fc, out + o_fmask, out + o_loss, wsf + W_SCORES);
    k_select<<<1, 256, 0, stream>>>(wsf + W_SCORES, wsf + W_CUTOFF);
    k_segments<<<1, 128, 0, stream>>>(out + o_loss, wsf + W_CUTOFF, segs, counts);
    k_emit<<<1, 128, 0, stream>>>(counts, segs, rec_b, rec_last, rec_e, total);
    k_gather_atoms<<<(A * 7680 + T - 1) / T, T, 0, stream>>>(rec_b, rec_last, rec_e, x,
                                                             out + o_atoms, out + o_mask, A);
    k_ae<<<A, 64, 0, stream>>>(rec_b, rec_last, rec_e, wsf + W_BRIDGE,
                               ae1_w, ae1_b, ae2_w, ae2_b, ae3_w, ae3_b,
                               ad1_w, ad1_b, hd);
    dim3 g2((A + 31) / 32, 30);
    k_ad2<<<g2, 256, 0, stream>>>(hd, ad2_w, ad2_b, out + o_atom_gen, A);
    k_decoder<<<NWIN, 64, 0, stream>>>(wsf + W_BRIDGE, d1_w, d1_b, d2_w, d2_b, out + o_imu_gen);
}

// Round 3
// 1243.262 us; speedup vs baseline: 1.6667x; 1.5457x over previous
//
#include <hip/hip_runtime.h>
#include <math.h>

// ---------------------------------------------------------------------------
// AtomicHAR pipeline, fp32.
// bs=128 seq=128 C=6 L=20 N=16384 D=64 H=256 MAL=10 Wtot=1280
// ---------------------------------------------------------------------------

#define NWIN 16384   // bs*seq
#define SEQ  128
#define BS   128
#define KSEL 3276    // int(16384*0.2)
#define SEGSTRIDE 160    // worst-case segments per batch ~140
#define RECCAP 18432     // worst-case total segments

// ---------------- fused encoder: conv1+pool, conv2+pool, conv3+pool, bridge --
// 4 waves/block, one window n per wave. Weights staged transposed in LDS.
__global__ __launch_bounds__(256) void k_encoder(
        const float* __restrict__ x,
        const float* __restrict__ c1w, const float* __restrict__ c1b,
        const float* __restrict__ c2w, const float* __restrict__ c2b,
        const float* __restrict__ c3w, const float* __restrict__ c3b,
        const float* __restrict__ brw, const float* __restrict__ brb,
        float* __restrict__ bridge, float* __restrict__ out_resh,
        float* __restrict__ out_fin) {
    __shared__ float c1wt[288];    // (ic*3+dk)*16 + oc
    __shared__ float c2wt[1536];   // (ic*3+dk)*32 + oc
    __shared__ float c3wt[3072];   // (ic*3+dk)*32 + oc
    __shared__ float brws[4096];   // i*64 + d
    __shared__ float c1bs[16], c2bs[32], c3bs[32], brbs[64];
    __shared__ float xs[4][128], c1s[4][160], c2s[4][160], c3s[4][64];

    int tid = threadIdx.x;
    for (int i = tid; i < 288; i += 256) {
        int oc = i / 18, r = i - oc * 18, ic = r / 3, dk = r - ic * 3;
        c1wt[(ic * 3 + dk) * 16 + oc] = c1w[i];
    }
    for (int i = tid; i < 1536; i += 256) {
        int oc = i / 48, r = i - oc * 48, ic = r / 3, dk = r - ic * 3;
        c2wt[(ic * 3 + dk) * 32 + oc] = c2w[i];
    }
    for (int i = tid; i < 3072; i += 256) {
        int oc = i / 96, r = i - oc * 96, ic = r / 3, dk = r - ic * 3;
        c3wt[(ic * 3 + dk) * 32 + oc] = c3w[i];
    }
    for (int i = tid; i < 4096; i += 256) brws[i] = brw[i];
    if (tid < 16) c1bs[tid] = c1b[tid];
    else if (tid < 48) c2bs[tid - 16] = c2b[tid - 16];
    else if (tid < 80) c3bs[tid - 48] = c3b[tid - 48];
    else if (tid < 144) brbs[tid - 80] = brb[tid - 80];

    int wv = tid >> 6, lane = tid & 63;
    int n = blockIdx.x * 4 + wv;
    const float* xr = x + (size_t)n * 120;
    if (lane < 60) ((float2*)&xs[wv][0])[lane] = ((const float2*)xr)[lane];
    __syncthreads();

    // conv1: oc = lane>>2 (16), tg = lane&3; t = tg + 4j
    {
        int oc = lane >> 2, tg = lane & 3;
        float bb = c1bs[oc];
        float acc[3][2];
#pragma unroll
        for (int j = 0; j < 3; ++j) { acc[j][0] = bb; acc[j][1] = bb; }
        for (int ic = 0; ic < 6; ++ic) {
            float w0 = c1wt[(ic * 3 + 0) * 16 + oc];
            float w1 = c1wt[(ic * 3 + 1) * 16 + oc];
            float w2 = c1wt[(ic * 3 + 2) * 16 + oc];
            const float* ar = &xs[wv][ic * 20];
#pragma unroll
            for (int j = 0; j < 3; ++j) {
                int t = tg + 4 * j;
                if (t < 10) {
#pragma unroll
                    for (int q = 0; q < 2; ++q) {
                        int p = 2 * t + q;
                        float a0 = (p >= 1) ? ar[p - 1] : 0.f;
                        float a1 = ar[p];
                        float a2 = (p + 1 < 20) ? ar[p + 1] : 0.f;
                        acc[j][q] += a0 * w0 + a1 * w1 + a2 * w2;
                    }
                }
            }
        }
#pragma unroll
        for (int j = 0; j < 3; ++j) {
            int t = tg + 4 * j;
            if (t < 10) c1s[wv][oc * 10 + t] = fmaxf(fmaxf(acc[j][0], acc[j][1]), 0.f);
        }
    }
    __syncthreads();

    // conv2: oc = lane>>1 (32), tg = lane&1; t = tg + 2j
    {
        int oc = lane >> 1, tg = lane & 1;
        float bb = c2bs[oc];
        float acc[3][2];
#pragma unroll
        for (int j = 0; j < 3; ++j) { acc[j][0] = bb; acc[j][1] = bb; }
        for (int ic = 0; ic < 16; ++ic) {
            float w0 = c2wt[(ic * 3 + 0) * 32 + oc];
            float w1 = c2wt[(ic * 3 + 1) * 32 + oc];
            float w2 = c2wt[(ic * 3 + 2) * 32 + oc];
            const float* ar = &c1s[wv][ic * 10];
#pragma unroll
            for (int j = 0; j < 3; ++j) {
                int t = tg + 2 * j;
                if (t < 5) {
#pragma unroll
                    for (int q = 0; q < 2; ++q) {
                        int p = 2 * t + q;
                        float a0 = (p >= 1) ? ar[p - 1] : 0.f;
                        float a1 = ar[p];
                        float a2 = (p + 1 < 10) ? ar[p + 1] : 0.f;
                        acc[j][q] += a0 * w0 + a1 * w1 + a2 * w2;
                    }
                }
            }
        }
#pragma unroll
        for (int j = 0; j < 3; ++j) {
            int t = tg + 2 * j;
            if (t < 5) c2s[wv][oc * 5 + t] = fmaxf(fmaxf(acc[j][0], acc[j][1]), 0.f);
        }
    }
    __syncthreads();

    // conv3: oc = lane>>1, tp = lane&1; output d = lane
    {
        int oc = lane >> 1, tp = lane & 1;
        float bb = c3bs[oc];
        float acc0 = bb, acc1 = bb;
        for (int ic = 0; ic < 32; ++ic) {
            float w0 = c3wt[(ic * 3 + 0) * 32 + oc];
            float w1 = c3wt[(ic * 3 + 1) * 32 + oc];
            float w2 = c3wt[(ic * 3 + 2) * 32 + oc];
            const float* ar = &c2s[wv][ic * 5];
            {   // q = 0: p = 2tp
                int p = 2 * tp;
                float a0 = (p >= 1) ? ar[p - 1] : 0.f;
                acc0 += a0 * w0 + ar[p] * w1 + ar[p + 1] * w2;
            }
            {   // q = 1: p = 2tp+1
                int p = 2 * tp + 1;
                acc1 += ar[p - 1] * w0 + ar[p] * w1 + ((p + 1 < 5) ? ar[p + 1] : 0.f) * w2;
            }
        }
        c3s[wv][lane] = fmaxf(fmaxf(acc0, acc1), 0.f);
    }
    __syncthreads();

    // bridge: d = lane
    {
        float acc = brbs[lane];
        for (int i = 0; i < 64; ++i) acc += c3s[wv][i] * brws[i * 64 + lane];
        float v = 1.f / (1.f + expf(-acc));
        size_t o = (size_t)n * 64 + lane;
        bridge[o] = v; out_resh[o] = v; out_fin[o] = v;
    }
}

__global__ void k_f1(const float* __restrict__ bridge, const float* __restrict__ w,
                     const float* __restrict__ b, float* __restrict__ feat) {
    int n = blockIdx.x, h = threadIdx.x;
    int s = n & (SEQ - 1);
    float acc = b[h];
    if (s > 0) {
        const float* br = bridge + (n - 1) * 64;
        for (int d = 0; d < 64; ++d) acc += br[d] * w[d * 256 + h];
    }
    feat[n * 256 + h] = fmaxf(acc, 0.f);
}

__global__ void k_f2_loss(const float* __restrict__ feat, const float* __restrict__ bridge,
                          const float* __restrict__ w, const float* __restrict__ b,
                          const float* __restrict__ imu_mask,
                          float* __restrict__ out_fc, float* __restrict__ out_fmask,
                          float* __restrict__ out_loss, float* __restrict__ scores) {
    int n = blockIdx.x, d = threadIdx.x;
    const float* fr = feat + n * 256;
    float acc = b[d];
    for (int h = 0; h < 256; ++h) acc += fr[h] * w[h * 64 + d];
    out_fc[n * 64 + d] = acc;
    int s = n & (SEQ - 1);
    float mval = (s == 0) ? 0.f : imu_mask[(size_t)n * 120];
    out_fmask[n * 64 + d] = mval;
    float diff = (acc - bridge[n * 64 + d]) * mval;
    float sq = diff * diff;
#pragma unroll
    for (int off = 32; off; off >>= 1) sq += __shfl_down(sq, off);
    if (d == 0) {
        float loss = sq * (1.f / 64.f);
        out_loss[n] = loss;
        scores[n] = loss * mval;
    }
}

// exact k-th largest via radix select on float bits (scores >= 0). 1 block x 256.
__global__ void k_select(const float* __restrict__ scores, float* __restrict__ cutoff) {
    __shared__ unsigned hist[256];
    __shared__ unsigned sh_prefix;
    __shared__ int sh_k;
    int tid = threadIdx.x;
    if (tid == 0) { sh_prefix = 0u; sh_k = KSEL; }
    __syncthreads();
    for (int shift = 24; shift >= 0; shift -= 8) {
        hist[tid] = 0u;
        __syncthreads();
        unsigned prefix = sh_prefix;
        unsigned pmask = (shift == 24) ? 0u : (0xFFFFFFFFu << (shift + 8));
        for (int i = tid; i < NWIN; i += 256) {
            unsigned u = __float_as_uint(scores[i]);
            if ((u & pmask) == prefix) atomicAdd(&hist[(u >> shift) & 255u], 1u);
        }
        __syncthreads();
        if (tid == 0) {
            int kk = sh_k;
            for (int bin = 255; bin >= 0; --bin) {
                int c = (int)hist[bin];
                if (kk <= c) { sh_prefix = prefix | ((unsigned)bin << shift); sh_k = kk; break; }
                kk -= c;
            }
        }
        __syncthreads();
    }
    if (tid == 0) *cutoff = __uint_as_float(sh_prefix);
}

// per-batch segmentation with gap-fill. 1 block x 128 (thread per batch).
__global__ void k_segments(const float* __restrict__ loss, const float* __restrict__ cutoff_p,
                           int* __restrict__ segs, int* __restrict__ counts) {
    int b = threadIdx.x;
    if (b >= BS) return;
    float cutoff = *cutoff_p;
    int* my = segs + b * SEGSTRIDE;
    int cnt = 0, prev = 0;
    bool has = false;
    for (int s = 0; s < SEQ; ++s) {
        if (loss[b * SEQ + s] > cutoff) {
            if (has) {
                if (s - prev > 10) {
                    my[cnt++] = prev;
                    int cur = prev;
                    while (cur < s) {
                        cur += 10;
                        if (cur >= s) break;
                        my[cnt++] = cur;
                    }
                } else {
                    my[cnt++] = prev;
                }
            }
            has = true; prev = s;
        }
    }
    if (has) my[cnt++] = prev;
    counts[b] = cnt;
}

// prefix-scan counts, emit (b,last,e) records. 1 block x 128.
__global__ void k_emit(const int* __restrict__ counts, const int* __restrict__ segs,
                       int* __restrict__ rec_b, int* __restrict__ rec_last,
                       int* __restrict__ rec_e, int* __restrict__ total_out) {
    __shared__ int offs[BS + 1];
    int tid = threadIdx.x;
    if (tid == 0) {
        int acc = 0;
        for (int b = 0; b < BS; ++b) { offs[b] = acc; acc += counts[b]; }
        offs[BS] = acc;
        *total_out = acc;
        if (acc == 0) { rec_b[0] = 0; rec_last[0] = 0; rec_e[0] = 0; }  // fallback dummy
    }
    __syncthreads();
    int b = tid;
    int o = offs[b], c = counts[b];
    for (int j = 0; j < c; ++j) {
        int idx = o + j;
        if (idx >= RECCAP) break;
        rec_b[idx] = b;
        rec_last[idx] = (j > 0) ? segs[b * SEGSTRIDE + j - 1] : 0;
        rec_e[idx] = segs[b * SEGSTRIDE + j];
    }
}

// imu_atoms + mask: (A, 6, 1280)
__global__ void k_gather_atoms(const int* __restrict__ rec_b, const int* __restrict__ rec_last,
                               const int* __restrict__ rec_e, const float* __restrict__ x,
                               float* __restrict__ out_atoms, float* __restrict__ out_mask, int A) {
    int gid = blockIdx.x * blockDim.x + threadIdx.x;
    if (gid >= A * 7680) return;
    int a = gid / 7680, rem = gid % 7680, c = rem / 1280, wcol = rem % 1280;
    int b = rec_b[a], last = rec_last[a], e = rec_e[a];
    int W = (e - last) * 20;
    int sc = wcol - (1280 - W);
    float v = 0.f, m = 0.f;
    if (sc >= 0 && sc < W) {
        int t = sc / 20, l = sc % 20;
        v = x[((b * SEQ + last + t) * 6 + c) * 20 + l];
        m = 1.f;
    }
    out_atoms[gid] = v;
    out_mask[gid] = m;
}

// autoencoder per segment: gather af(64,10) from bridge -> conv/pool/conv -> emb(32) -> hd(256)
__global__ void k_ae(const int* __restrict__ rec_b, const int* __restrict__ rec_last,
                     const int* __restrict__ rec_e, const float* __restrict__ bridge,
                     const float* __restrict__ ae1w, const float* __restrict__ ae1b,
                     const float* __restrict__ ae2w, const float* __restrict__ ae2b,
                     const float* __restrict__ ae3w, const float* __restrict__ ae3b,
                     const float* __restrict__ ad1w, const float* __restrict__ ad1b,
                     float* __restrict__ hd) {
    __shared__ float af_s[640];
    __shared__ float c1s[320];
    __shared__ float h2s[80];
    __shared__ float embs[32];
    int a = blockIdx.x, tid = threadIdx.x;
    int b = rec_b[a], last = rec_last[a], e = rec_e[a];
    for (int i = tid; i < 640; i += 64) {
        int d = i / 10, r = i % 10;
        int src = e - 10 + r;
        af_s[i] = (src >= last) ? bridge[(b * SEQ + src) * 64 + d] : 0.f;
    }
    __syncthreads();
    for (int idx = tid; idx < 320; idx += 64) {
        int o = idx / 10, p = idx % 10;
        float acc = ae1b[o];
        for (int ic = 0; ic < 64; ++ic) {
            const float* wr = ae1w + o * 192 + ic * 3;
            const float* ar = af_s + ic * 10;
#pragma unroll
            for (int dk = 0; dk < 3; ++dk) {
                int pp = p + dk - 1;
                if (pp >= 0 && pp < 10) acc += ar[pp] * wr[dk];
            }
        }
        c1s[o * 10 + p] = fmaxf(acc, 0.f);
    }
    __syncthreads();
    for (int idx = tid; idx < 80; idx += 64) {
        int c = idx / 5, t = idx % 5;
        float acc = ae2b[c];
        for (int ic = 0; ic < 32; ++ic) {
#pragma unroll
            for (int dk = 0; dk < 3; ++dk) {
                int tt = t + dk - 1;
                if (tt >= 0 && tt < 5) {
                    float m = fmaxf(c1s[ic * 10 + 2 * tt], c1s[ic * 10 + 2 * tt + 1]);
                    acc += m * ae2w[c * 96 + ic * 3 + dk];
                }
            }
        }
        h2s[c * 5 + t] = fmaxf(acc, 0.f);
    }
    __syncthreads();
    if (tid < 32) {
        float acc = ae3b[tid];
        for (int i = 0; i < 80; ++i) acc += h2s[i] * ae3w[i * 32 + tid];
        embs[tid] = acc;   // no relu on emb
    }
    __syncthreads();
    for (int idx = tid; idx < 256; idx += 64) {
        float acc = ad1b[idx];
#pragma unroll
        for (int o = 0; o < 32; ++o) acc += embs[o] * ad1w[o * 256 + idx];
        hd[a * 256 + idx] = fmaxf(acc, 0.f);
    }
}

// atom_gen = hd(A,256) @ ad2_w(256,7680) + ad2_b.
__global__ __launch_bounds__(256) void k_ad2(const float* __restrict__ hd,
                                             const float* __restrict__ w,
                                             const float* __restrict__ bias,
                                             float* __restrict__ out, int A) {
    __shared__ float hs[32][256];
    int jq = threadIdx.x & 63;          // 0..63
    int q  = threadIdx.x >> 6;          // 0..3
    int jw = blockIdx.y * 64 + jq;      // float4 index into a row of w
    int j0 = jw * 4;
    int a0 = blockIdx.x * 32;
    for (int idx = threadIdx.x; idx < 32 * 256; idx += 256) {
        int row = idx >> 8, col = idx & 255;
        hs[row][col] = (a0 + row < A) ? hd[(a0 + row) * 256 + col] : 0.f;
    }
    __syncthreads();
    float acc[8][4] = {};
    const float4* w4 = (const float4*)w;
    for (int k = 0; k < 256; k += 4) {
        float4 wv0 = w4[(size_t)(k + 0) * 1920 + jw];
        float4 wv1 = w4[(size_t)(k + 1) * 1920 + jw];
        float4 wv2 = w4[(size_t)(k + 2) * 1920 + jw];
        float4 wv3 = w4[(size_t)(k + 3) * 1920 + jw];
#pragma unroll
        for (int i = 0; i < 8; ++i) {
            float4 h4 = *(const float4*)&hs[q + i * 4][k];
            acc[i][0] += h4.x * wv0.x + h4.y * wv1.x + h4.z * wv2.x + h4.w * wv3.x;
            acc[i][1] += h4.x * wv0.y + h4.y * wv1.y + h4.z * wv2.y + h4.w * wv3.y;
            acc[i][2] += h4.x * wv0.z + h4.y * wv1.z + h4.z * wv2.z + h4.w * wv3.z;
            acc[i][3] += h4.x * wv0.w + h4.y * wv1.w + h4.z * wv2.w + h4.w * wv3.w;
        }
    }
    float4 bb = ((const float4*)bias)[jw];
#pragma unroll
    for (int i = 0; i < 8; ++i) {
        int a = a0 + q + i * 4;
        if (a < A) {
            float4 r;
            r.x = acc[i][0] + bb.x;
            r.y = acc[i][1] + bb.y;
            r.z = acc[i][2] + bb.z;
            r.w = acc[i][3] + bb.w;
            *(float4*)&out[(size_t)a * 7680 + j0] = r;
        }
    }
}

// decoder: 4 waves/block, one n per wave; weights staged transposed in LDS.
__global__ __launch_bounds__(256) void k_decoder(const float* __restrict__ bridge,
                          const float* __restrict__ d1w, const float* __restrict__ d1b,
                          const float* __restrict__ d2w, const float* __restrict__ d2b,
                          float* __restrict__ out) {
    __shared__ float d1wt[16 * 5 * 33];   // (c*5+kk)*33 + o   (pad 33 breaks bank alias)
    __shared__ float d2wt[576];           // (ic*3+dk)*6 + oc
    __shared__ float d1bs[32], d2bs[8];
    __shared__ float brs[4][64];
    __shared__ float gs[4][640];
    int tid = threadIdx.x;
    for (int i = tid; i < 2560; i += 256) {
        int c = i / 160, r = i - c * 160, o = r / 5, kk = r - o * 5;
        d1wt[(c * 5 + kk) * 33 + o] = d1w[i];
    }
    for (int i = tid; i < 576; i += 256) {
        int oc = i / 96, r = i - oc * 96, ic = r / 3, dk = r - ic * 3;
        d2wt[(ic * 3 + dk) * 6 + oc] = d2w[i];
    }
    if (tid < 32) d1bs[tid] = d1b[tid];
    else if (tid < 38) d2bs[tid - 32] = d2b[tid - 32];
    int wv = tid >> 6, lane = tid & 63;
    int n = blockIdx.x * 4 + wv;
    brs[wv][lane] = bridge[(size_t)n * 64 + lane];
    __syncthreads();
    for (int idx = lane; idx < 640; idx += 64) {
        int o = idx / 20, p = idx - o * 20, i = p / 5, kk = p - i * 5;
        float acc = d1bs[o];
#pragma unroll
        for (int c = 0; c < 16; ++c) acc += brs[wv][c * 4 + i] * d1wt[(c * 5 + kk) * 33 + o];
        gs[wv][idx] = fmaxf(acc, 0.f);
    }
    __syncthreads();
    for (int idx = lane; idx < 120; idx += 64) {
        int oc = idx / 20, t = idx - oc * 20;
        float acc = d2bs[oc];
        for (int ic = 0; ic < 32; ++ic) {
            const float* gr = &gs[wv][ic * 20];
            float a0 = (t >= 1) ? gr[t - 1] : 0.f;
            float a1 = gr[t];
            float a2 = (t + 1 < 20) ? gr[t + 1] : 0.f;
            acc += a0 * d2wt[(ic * 3 + 0) * 6 + oc]
                 + a1 * d2wt[(ic * 3 + 1) * 6 + oc]
                 + a2 * d2wt[(ic * 3 + 2) * 6 + oc];
        }
        out[(size_t)n * 120 + idx] = acc;
    }
}

// ---------------------------------------------------------------------------
extern "C" void kernel_launch(void* const* d_in, const int* in_sizes, int n_in,
                              void* d_out, int out_size, void* d_ws, size_t ws_size,
                              hipStream_t stream) {
    const float* x        = (const float*)d_in[0];
    const float* imu_mask = (const float*)d_in[1];
    const float* c1_w = (const float*)d_in[3];
    const float* c1_b = (const float*)d_in[4];
    const float* c2_w = (const float*)d_in[5];
    const float* c2_b = (const float*)d_in[6];
    const float* c3_w = (const float*)d_in[7];
    const float* c3_b = (const float*)d_in[8];
    const float* br_w = (const float*)d_in[9];
    const float* br_b = (const float*)d_in[10];
    const float* f1_w = (const float*)d_in[11];
    const float* f1_b = (const float*)d_in[12];
    const float* f2_w = (const float*)d_in[13];
    const float* f2_b = (const float*)d_in[14];
    const float* d1_w = (const float*)d_in[15];
    const float* d1_b = (const float*)d_in[16];
    const float* d2_w = (const float*)d_in[17];
    const float* d2_b = (const float*)d_in[18];
    const float* ae1_w = (const float*)d_in[19];
    const float* ae1_b = (const float*)d_in[20];
    const float* ae2_w = (const float*)d_in[21];
    const float* ae2_b = (const float*)d_in[22];
    const float* ae3_w = (const float*)d_in[23];
    const float* ae3_b = (const float*)d_in[24];
    const float* ad1_w = (const float*)d_in[25];
    const float* ad1_b = (const float*)d_in[26];
    const float* ad2_w = (const float*)d_in[27];
    const float* ad2_b = (const float*)d_in[28];

    // A from out_size: out_size = 6,176,768 + 23,040*A
    int A = (out_size - 6176768) / 23040;
    if (A < 1) A = 1;

    float* out = (float*)d_out;
    size_t o_imu_gen  = 0;
    size_t o_atom_gen = 1966080;
    size_t o_mask     = o_atom_gen + (size_t)A * 7680;
    size_t o_atoms    = o_mask + (size_t)A * 7680;
    size_t o_resh     = o_atoms + (size_t)A * 7680;
    size_t o_fin      = o_resh + 1048576;
    size_t o_fc       = o_fin + 1048576;
    size_t o_fmask    = o_fc + 1048576;
    size_t o_loss     = o_fmask + 1048576;

    // workspace layout (float units)
    float* wsf = (float*)d_ws;
    int*   wsi = (int*)d_ws;
    const size_t W_BRIDGE = 0;                       // 1,048,576
    const size_t W_FEAT   = W_BRIDGE + 1048576;      // 4,194,304
    const size_t W_SCORES = W_FEAT + 4194304;        // 16,384
    const size_t W_CUTOFF = W_SCORES + 16384;        // 64
    const size_t MW       = W_CUTOFF + 64;           // meta (int units)
    int* counts   = wsi + MW;
    int* total    = wsi + MW + 128;
    int* segs     = wsi + MW + 192;                          // BS*SEGSTRIDE = 20480
    int* rec_b    = wsi + MW + 192 + BS * SEGSTRIDE;
    int* rec_last = rec_b + RECCAP;
    int* rec_e    = rec_last + RECCAP;
    float* hd     = wsf + MW + 192 + BS * SEGSTRIDE + 3 * RECCAP;  // A*256 floats

    hipMemsetAsync(rec_b, 0, 3 * RECCAP * sizeof(int), stream);

    const int T = 256;
    k_encoder<<<NWIN / 4, 256, 0, stream>>>(x, c1_w, c1_b, c2_w, c2_b, c3_w, c3_b,
                                            br_w, br_b, wsf + W_BRIDGE,
                                            out + o_resh, out + o_fin);
    k_f1<<<NWIN, 256, 0, stream>>>(wsf + W_BRIDGE, f1_w, f1_b, wsf + W_FEAT);
    k_f2_loss<<<NWIN, 64, 0, stream>>>(wsf + W_FEAT, wsf + W_BRIDGE, f2_w, f2_b, imu_mask,
                                       out + o_fc, out + o_fmask, out + o_loss, wsf + W_SCORES);
    k_select<<<1, 256, 0, stream>>>(wsf + W_SCORES, wsf + W_CUTOFF);
    k_segments<<<1, 128, 0, stream>>>(out + o_loss, wsf + W_CUTOFF, segs, counts);
    k_emit<<<1, 128, 0, stream>>>(counts, segs, rec_b, rec_last, rec_e, total);
    k_gather_atoms<<<(A * 7680 + T - 1) / T, T, 0, stream>>>(rec_b, rec_last, rec_e, x,
                                                             out + o_atoms, out + o_mask, A);
    k_ae<<<A, 64, 0, stream>>>(rec_b, rec_last, rec_e, wsf + W_BRIDGE,
                               ae1_w, ae1_b, ae2_w, ae2_b, ae3_w, ae3_b,
                               ad1_w, ad1_b, hd);
    dim3 g2((A + 31) / 32, 30);
    k_ad2<<<g2, 256, 0, stream>>>(hd, ad2_w, ad2_b, out + o_atom_gen, A);
    k_decoder<<<NWIN / 4, 256, 0, stream>>>(wsf + W_BRIDGE, d1_w, d1_b, d2_w, d2_b,
                                            out + o_imu_gen);
}

// Round 4
// 1243.024 us; speedup vs baseline: 1.6670x; 1.0002x over previous
//
#include <hip/hip_runtime.h>
#include <math.h>

// ---------------------------------------------------------------------------
// AtomicHAR pipeline. fp32 everywhere except the post-selection ad2 GEMM
// (bf16 MFMA — cannot affect segment selection; tolerance 9.9e-2 vs ~3e-3 err).
// bs=128 seq=128 C=6 L=20 N=16384 D=64 H=256 MAL=10 Wtot=1280
// ---------------------------------------------------------------------------

#define NWIN 16384   // bs*seq
#define SEQ  128
#define BS   128
#define KSEL 3276    // int(16384*0.2)
#define SEGSTRIDE 160    // worst-case segments per batch ~140
#define RECCAP 18432     // worst-case total segments

typedef __attribute__((ext_vector_type(8))) short short8v;
typedef __attribute__((ext_vector_type(4))) float float4v;

__device__ inline unsigned short bf16rne(float f) {
    unsigned u = __float_as_uint(f);
    unsigned r = u + 0x7FFFu + ((u >> 16) & 1u);
    return (unsigned short)(r >> 16);
}

// ---------------- fused encoder: conv1+pool, conv2+pool, conv3+pool, bridge --
__global__ __launch_bounds__(256) void k_encoder(
        const float* __restrict__ x,
        const float* __restrict__ c1w, const float* __restrict__ c1b,
        const float* __restrict__ c2w, const float* __restrict__ c2b,
        const float* __restrict__ c3w, const float* __restrict__ c3b,
        const float* __restrict__ brw, const float* __restrict__ brb,
        float* __restrict__ bridge, float* __restrict__ out_resh,
        float* __restrict__ out_fin) {
    __shared__ float c1wt[288];    // (ic*3+dk)*16 + oc
    __shared__ float c2wt[1536];   // (ic*3+dk)*32 + oc
    __shared__ float c3wt[3072];   // (ic*3+dk)*32 + oc
    __shared__ float brws[4096];   // i*64 + d
    __shared__ float c1bs[16], c2bs[32], c3bs[32], brbs[64];
    __shared__ float xs[4][128], c1s[4][160], c2s[4][160], c3s[4][64];

    int tid = threadIdx.x;
    for (int i = tid; i < 288; i += 256) {
        int oc = i / 18, r = i - oc * 18, ic = r / 3, dk = r - ic * 3;
        c1wt[(ic * 3 + dk) * 16 + oc] = c1w[i];
    }
    for (int i = tid; i < 1536; i += 256) {
        int oc = i / 48, r = i - oc * 48, ic = r / 3, dk = r - ic * 3;
        c2wt[(ic * 3 + dk) * 32 + oc] = c2w[i];
    }
    for (int i = tid; i < 3072; i += 256) {
        int oc = i / 96, r = i - oc * 96, ic = r / 3, dk = r - ic * 3;
        c3wt[(ic * 3 + dk) * 32 + oc] = c3w[i];
    }
    for (int i = tid; i < 4096; i += 256) brws[i] = brw[i];
    if (tid < 16) c1bs[tid] = c1b[tid];
    else if (tid < 48) c2bs[tid - 16] = c2b[tid - 16];
    else if (tid < 80) c3bs[tid - 48] = c3b[tid - 48];
    else if (tid < 144) brbs[tid - 80] = brb[tid - 80];

    int wv = tid >> 6, lane = tid & 63;
    int n = blockIdx.x * 4 + wv;
    const float* xr = x + (size_t)n * 120;
    if (lane < 60) ((float2*)&xs[wv][0])[lane] = ((const float2*)xr)[lane];
    __syncthreads();

    // conv1
    {
        int oc = lane >> 2, tg = lane & 3;
        float bb = c1bs[oc];
        float acc[3][2];
#pragma unroll
        for (int j = 0; j < 3; ++j) { acc[j][0] = bb; acc[j][1] = bb; }
        for (int ic = 0; ic < 6; ++ic) {
            float w0 = c1wt[(ic * 3 + 0) * 16 + oc];
            float w1 = c1wt[(ic * 3 + 1) * 16 + oc];
            float w2 = c1wt[(ic * 3 + 2) * 16 + oc];
            const float* ar = &xs[wv][ic * 20];
#pragma unroll
            for (int j = 0; j < 3; ++j) {
                int t = tg + 4 * j;
                if (t < 10) {
#pragma unroll
                    for (int q = 0; q < 2; ++q) {
                        int p = 2 * t + q;
                        float a0 = (p >= 1) ? ar[p - 1] : 0.f;
                        float a1 = ar[p];
                        float a2 = (p + 1 < 20) ? ar[p + 1] : 0.f;
                        acc[j][q] += a0 * w0 + a1 * w1 + a2 * w2;
                    }
                }
            }
        }
#pragma unroll
        for (int j = 0; j < 3; ++j) {
            int t = tg + 4 * j;
            if (t < 10) c1s[wv][oc * 10 + t] = fmaxf(fmaxf(acc[j][0], acc[j][1]), 0.f);
        }
    }
    __syncthreads();

    // conv2
    {
        int oc = lane >> 1, tg = lane & 1;
        float bb = c2bs[oc];
        float acc[3][2];
#pragma unroll
        for (int j = 0; j < 3; ++j) { acc[j][0] = bb; acc[j][1] = bb; }
        for (int ic = 0; ic < 16; ++ic) {
            float w0 = c2wt[(ic * 3 + 0) * 32 + oc];
            float w1 = c2wt[(ic * 3 + 1) * 32 + oc];
            float w2 = c2wt[(ic * 3 + 2) * 32 + oc];
            const float* ar = &c1s[wv][ic * 10];
#pragma unroll
            for (int j = 0; j < 3; ++j) {
                int t = tg + 2 * j;
                if (t < 5) {
#pragma unroll
                    for (int q = 0; q < 2; ++q) {
                        int p = 2 * t + q;
                        float a0 = (p >= 1) ? ar[p - 1] : 0.f;
                        float a1 = ar[p];
                        float a2 = (p + 1 < 10) ? ar[p + 1] : 0.f;
                        acc[j][q] += a0 * w0 + a1 * w1 + a2 * w2;
                    }
                }
            }
        }
#pragma unroll
        for (int j = 0; j < 3; ++j) {
            int t = tg + 2 * j;
            if (t < 5) c2s[wv][oc * 5 + t] = fmaxf(fmaxf(acc[j][0], acc[j][1]), 0.f);
        }
    }
    __syncthreads();

    // conv3
    {
        int oc = lane >> 1, tp = lane & 1;
        float bb = c3bs[oc];
        float acc0 = bb, acc1 = bb;
        for (int ic = 0; ic < 32; ++ic) {
            float w0 = c3wt[(ic * 3 + 0) * 32 + oc];
            float w1 = c3wt[(ic * 3 + 1) * 32 + oc];
            float w2 = c3wt[(ic * 3 + 2) * 32 + oc];
            const float* ar = &c2s[wv][ic * 5];
            {
                int p = 2 * tp;
                float a0 = (p >= 1) ? ar[p - 1] : 0.f;
                acc0 += a0 * w0 + ar[p] * w1 + ar[p + 1] * w2;
            }
            {
                int p = 2 * tp + 1;
                acc1 += ar[p - 1] * w0 + ar[p] * w1 + ((p + 1 < 5) ? ar[p + 1] : 0.f) * w2;
            }
        }
        c3s[wv][lane] = fmaxf(fmaxf(acc0, acc1), 0.f);
    }
    __syncthreads();

    // bridge
    {
        float acc = brbs[lane];
        for (int i = 0; i < 64; ++i) acc += c3s[wv][i] * brws[i * 64 + lane];
        float v = 1.f / (1.f + expf(-acc));
        size_t o = (size_t)n * 64 + lane;
        bridge[o] = v; out_resh[o] = v; out_fin[o] = v;
    }
}

__global__ void k_f1(const float* __restrict__ bridge, const float* __restrict__ w,
                     const float* __restrict__ b, float* __restrict__ feat) {
    int n = blockIdx.x, h = threadIdx.x;
    int s = n & (SEQ - 1);
    float acc = b[h];
    if (s > 0) {
        const float* br = bridge + (n - 1) * 64;
        for (int d = 0; d < 64; ++d) acc += br[d] * w[d * 256 + h];
    }
    feat[n * 256 + h] = fmaxf(acc, 0.f);
}

__global__ void k_f2_loss(const float* __restrict__ feat, const float* __restrict__ bridge,
                          const float* __restrict__ w, const float* __restrict__ b,
                          const float* __restrict__ imu_mask,
                          float* __restrict__ out_fc, float* __restrict__ out_fmask,
                          float* __restrict__ out_loss, float* __restrict__ scores) {
    int n = blockIdx.x, d = threadIdx.x;
    const float* fr = feat + n * 256;
    float acc = b[d];
    for (int h = 0; h < 256; ++h) acc += fr[h] * w[h * 64 + d];
    out_fc[n * 64 + d] = acc;
    int s = n & (SEQ - 1);
    float mval = (s == 0) ? 0.f : imu_mask[(size_t)n * 120];
    out_fmask[n * 64 + d] = mval;
    float diff = (acc - bridge[n * 64 + d]) * mval;
    float sq = diff * diff;
#pragma unroll
    for (int off = 32; off; off >>= 1) sq += __shfl_down(sq, off);
    if (d == 0) {
        float loss = sq * (1.f / 64.f);
        out_loss[n] = loss;
        scores[n] = loss * mval;
    }
}

// exact k-th largest via radix select on float bits (scores >= 0). 1 block x 256.
__global__ void k_select(const float* __restrict__ scores, float* __restrict__ cutoff) {
    __shared__ unsigned hist[256];
    __shared__ unsigned sh_prefix;
    __shared__ int sh_k;
    int tid = threadIdx.x;
    if (tid == 0) { sh_prefix = 0u; sh_k = KSEL; }
    __syncthreads();
    for (int shift = 24; shift >= 0; shift -= 8) {
        hist[tid] = 0u;
        __syncthreads();
        unsigned prefix = sh_prefix;
        unsigned pmask = (shift == 24) ? 0u : (0xFFFFFFFFu << (shift + 8));
        for (int i = tid; i < NWIN; i += 256) {
            unsigned u = __float_as_uint(scores[i]);
            if ((u & pmask) == prefix) atomicAdd(&hist[(u >> shift) & 255u], 1u);
        }
        __syncthreads();
        if (tid == 0) {
            int kk = sh_k;
            for (int bin = 255; bin >= 0; --bin) {
                int c = (int)hist[bin];
                if (kk <= c) { sh_prefix = prefix | ((unsigned)bin << shift); sh_k = kk; break; }
                kk -= c;
            }
        }
        __syncthreads();
    }
    if (tid == 0) *cutoff = __uint_as_float(sh_prefix);
}

// per-batch segmentation with gap-fill. 1 block x 128 (thread per batch).
__global__ void k_segments(const float* __restrict__ loss, const float* __restrict__ cutoff_p,
                           int* __restrict__ segs, int* __restrict__ counts) {
    int b = threadIdx.x;
    if (b >= BS) return;
    float cutoff = *cutoff_p;
    int* my = segs + b * SEGSTRIDE;
    int cnt = 0, prev = 0;
    bool has = false;
    for (int s = 0; s < SEQ; ++s) {
        if (loss[b * SEQ + s] > cutoff) {
            if (has) {
                if (s - prev > 10) {
                    my[cnt++] = prev;
                    int cur = prev;
                    while (cur < s) {
                        cur += 10;
                        if (cur >= s) break;
                        my[cnt++] = cur;
                    }
                } else {
                    my[cnt++] = prev;
                }
            }
            has = true; prev = s;
        }
    }
    if (has) my[cnt++] = prev;
    counts[b] = cnt;
}

// prefix-scan counts, emit (b,last,e) records. 1 block x 128.
__global__ void k_emit(const int* __restrict__ counts, const int* __restrict__ segs,
                       int* __restrict__ rec_b, int* __restrict__ rec_last,
                       int* __restrict__ rec_e, int* __restrict__ total_out) {
    __shared__ int offs[BS + 1];
    int tid = threadIdx.x;
    if (tid == 0) {
        int acc = 0;
        for (int b = 0; b < BS; ++b) { offs[b] = acc; acc += counts[b]; }
        offs[BS] = acc;
        *total_out = acc;
        if (acc == 0) { rec_b[0] = 0; rec_last[0] = 0; rec_e[0] = 0; }  // fallback dummy
    }
    __syncthreads();
    int b = tid;
    int o = offs[b], c = counts[b];
    for (int j = 0; j < c; ++j) {
        int idx = o + j;
        if (idx >= RECCAP) break;
        rec_b[idx] = b;
        rec_last[idx] = (j > 0) ? segs[b * SEGSTRIDE + j - 1] : 0;
        rec_e[idx] = segs[b * SEGSTRIDE + j];
    }
}

// imu_atoms + mask: (A, 6, 1280)
__global__ void k_gather_atoms(const int* __restrict__ rec_b, const int* __restrict__ rec_last,
                               const int* __restrict__ rec_e, const float* __restrict__ x,
                               float* __restrict__ out_atoms, float* __restrict__ out_mask, int A) {
    int gid = blockIdx.x * blockDim.x + threadIdx.x;
    if (gid >= A * 7680) return;
    int a = gid / 7680, rem = gid % 7680, c = rem / 1280, wcol = rem % 1280;
    int b = rec_b[a], last = rec_last[a], e = rec_e[a];
    int W = (e - last) * 20;
    int sc = wcol - (1280 - W);
    float v = 0.f, m = 0.f;
    if (sc >= 0 && sc < W) {
        int t = sc / 20, l = sc % 20;
        v = x[((b * SEQ + last + t) * 6 + c) * 20 + l];
        m = 1.f;
    }
    out_atoms[gid] = v;
    out_mask[gid] = m;
}

// autoencoder per segment: gather af(64,10) from bridge -> conv/pool/conv -> emb(32)
// -> hd(256) stored as bf16 (k-major, MFMA-A-ready)
__global__ void k_ae(const int* __restrict__ rec_b, const int* __restrict__ rec_last,
                     const int* __restrict__ rec_e, const float* __restrict__ bridge,
                     const float* __restrict__ ae1w, const float* __restrict__ ae1b,
                     const float* __restrict__ ae2w, const float* __restrict__ ae2b,
                     const float* __restrict__ ae3w, const float* __restrict__ ae3b,
                     const float* __restrict__ ad1w, const float* __restrict__ ad1b,
                     unsigned short* __restrict__ hd) {
    __shared__ float af_s[640];
    __shared__ float c1s[320];
    __shared__ float h2s[80];
    __shared__ float embs[32];
    int a = blockIdx.x, tid = threadIdx.x;
    int b = rec_b[a], last = rec_last[a], e = rec_e[a];
    for (int i = tid; i < 640; i += 64) {
        int d = i / 10, r = i % 10;
        int src = e - 10 + r;
        af_s[i] = (src >= last) ? bridge[(b * SEQ + src) * 64 + d] : 0.f;
    }
    __syncthreads();
    for (int idx = tid; idx < 320; idx += 64) {
        int o = idx / 10, p = idx % 10;
        float acc = ae1b[o];
        for (int ic = 0; ic < 64; ++ic) {
            const float* wr = ae1w + o * 192 + ic * 3;
            const float* ar = af_s + ic * 10;
#pragma unroll
            for (int dk = 0; dk < 3; ++dk) {
                int pp = p + dk - 1;
                if (pp >= 0 && pp < 10) acc += ar[pp] * wr[dk];
            }
        }
        c1s[o * 10 + p] = fmaxf(acc, 0.f);
    }
    __syncthreads();
    for (int idx = tid; idx < 80; idx += 64) {
        int c = idx / 5, t = idx % 5;
        float acc = ae2b[c];
        for (int ic = 0; ic < 32; ++ic) {
#pragma unroll
            for (int dk = 0; dk < 3; ++dk) {
                int tt = t + dk - 1;
                if (tt >= 0 && tt < 5) {
                    float m = fmaxf(c1s[ic * 10 + 2 * tt], c1s[ic * 10 + 2 * tt + 1]);
                    acc += m * ae2w[c * 96 + ic * 3 + dk];
                }
            }
        }
        h2s[c * 5 + t] = fmaxf(acc, 0.f);
    }
    __syncthreads();
    if (tid < 32) {
        float acc = ae3b[tid];
        for (int i = 0; i < 80; ++i) acc += h2s[i] * ae3w[i * 32 + tid];
        embs[tid] = acc;   // no relu on emb
    }
    __syncthreads();
    for (int idx = tid; idx < 256; idx += 64) {
        float acc = ad1b[idx];
#pragma unroll
        for (int o = 0; o < 32; ++o) acc += embs[o] * ad1w[o * 256 + idx];
        hd[(size_t)a * 256 + idx] = bf16rne(fmaxf(acc, 0.f));
    }
}

// transpose + bf16-cast ad2_w (256 x 7680, row-major) -> wbT (7680 x 256, n-major)
__global__ __launch_bounds__(256) void k_wtrans(const float* __restrict__ w,
                                                unsigned short* __restrict__ wbT) {
    __shared__ float tile[64][65];
    int n0 = blockIdx.x * 64, k0 = blockIdx.y * 64;
    int tid = threadIdx.x;
    int c = tid & 63;
    for (int r = tid >> 6; r < 64; r += 4)
        tile[r][c] = w[(size_t)(k0 + r) * 7680 + n0 + c];
    __syncthreads();
    int n = tid >> 4, kq = (tid & 15) * 4;
    for (int nn = n; nn < 64; nn += 16) {
        unsigned p0 = (unsigned)bf16rne(tile[kq + 0][nn]) |
                      ((unsigned)bf16rne(tile[kq + 1][nn]) << 16);
        unsigned p1 = (unsigned)bf16rne(tile[kq + 2][nn]) |
                      ((unsigned)bf16rne(tile[kq + 3][nn]) << 16);
        unsigned* dst = (unsigned*)&wbT[(size_t)(n0 + nn) * 256 + k0 + kq];
        dst[0] = p0; dst[1] = p1;
    }
}

// atom_gen = hd(A,256)bf16 @ wbT^T + ad2_b via MFMA 16x16x32 bf16.
// Block: 256 thr = 4 waves; tile 64m x 64n; K=256 fully in LDS.
#define LSTR 264   // shorts per LDS row (256 + 8 pad): b128 frag reads 2-way (free)
__global__ __launch_bounds__(256) void k_ad2m(const unsigned short* __restrict__ hdb,
                                              const unsigned short* __restrict__ wbT,
                                              const float* __restrict__ bias,
                                              float* __restrict__ out, int A) {
    __shared__ unsigned short hs[64 * LSTR];
    __shared__ unsigned short wt[64 * LSTR];
    int tid = threadIdx.x;
    int m0 = blockIdx.x * 64;
    int n0 = blockIdx.y * 64;

    const unsigned* hdu = (const unsigned*)hdb;
    const unsigned* wtu = (const unsigned*)wbT;
#pragma unroll 4
    for (int i = 0; i < 32; ++i) {
        int flat = tid + 256 * i;          // 0..8191
        int row = flat >> 7, d = flat & 127;
        unsigned hv = 0;
        if (m0 + row < A) hv = hdu[(size_t)(m0 + row) * 128 + d];
        *(unsigned*)&hs[row * LSTR + d * 2] = hv;
        *(unsigned*)&wt[row * LSTR + d * 2] = wtu[(size_t)(n0 + row) * 128 + d];
    }
    __syncthreads();

    int wv = tid >> 6, lane = tid & 63;
    int rc = lane & 15;                  // m for A-frag, n for B-frag, col for C
    int koff = (lane >> 4) * 8;
    float4v acc[4];
#pragma unroll
    for (int i = 0; i < 4; ++i) acc[i] = (float4v){0.f, 0.f, 0.f, 0.f};

    const short* ha = (const short*)&hs[(wv * 16 + rc) * LSTR + koff];
#pragma unroll
    for (int s = 0; s < 8; ++s) {
        short8v a = *(const short8v*)(ha + s * 32);
#pragma unroll
        for (int nt = 0; nt < 4; ++nt) {
            short8v b = *(const short8v*)((const short*)&wt[(nt * 16 + rc) * LSTR + s * 32 + koff]);
            acc[nt] = __builtin_amdgcn_mfma_f32_16x16x32_bf16(a, b, acc[nt], 0, 0, 0);
        }
    }

    int quad = lane >> 4;
#pragma unroll
    for (int nt = 0; nt < 4; ++nt) {
        int n = n0 + nt * 16 + rc;
        float bb = bias[n];
#pragma unroll
        for (int r = 0; r < 4; ++r) {
            int m = m0 + wv * 16 + quad * 4 + r;
            if (m < A) out[(size_t)m * 7680 + n] = acc[nt][r] + bb;
        }
    }
}

// decoder: 4 waves/block, one n per wave; weights staged transposed in LDS.
__global__ __launch_bounds__(256) void k_decoder(const float* __restrict__ bridge,
                          const float* __restrict__ d1w, const float* __restrict__ d1b,
                          const float* __restrict__ d2w, const float* __restrict__ d2b,
                          float* __restrict__ out) {
    __shared__ float d1wt[16 * 5 * 33];   // (c*5+kk)*33 + o
    __shared__ float d2wt[576];           // (ic*3+dk)*6 + oc
    __shared__ float d1bs[32], d2bs[8];
    __shared__ float brs[4][64];
    __shared__ float gs[4][640];
    int tid = threadIdx.x;
    for (int i = tid; i < 2560; i += 256) {
        int c = i / 160, r = i - c * 160, o = r / 5, kk = r - o * 5;
        d1wt[(c * 5 + kk) * 33 + o] = d1w[i];
    }
    for (int i = tid; i < 576; i += 256) {
        int oc = i / 96, r = i - oc * 96, ic = r / 3, dk = r - ic * 3;
        d2wt[(ic * 3 + dk) * 6 + oc] = d2w[i];
    }
    if (tid < 32) d1bs[tid] = d1b[tid];
    else if (tid < 38) d2bs[tid - 32] = d2b[tid - 32];
    int wv = tid >> 6, lane = tid & 63;
    int n = blockIdx.x * 4 + wv;
    brs[wv][lane] = bridge[(size_t)n * 64 + lane];
    __syncthreads();
    for (int idx = lane; idx < 640; idx += 64) {
        int o = idx / 20, p = idx - o * 20, i = p / 5, kk = p - i * 5;
        float acc = d1bs[o];
#pragma unroll
        for (int c = 0; c < 16; ++c) acc += brs[wv][c * 4 + i] * d1wt[(c * 5 + kk) * 33 + o];
        gs[wv][idx] = fmaxf(acc, 0.f);
    }
    __syncthreads();
    for (int idx = lane; idx < 120; idx += 64) {
        int oc = idx / 20, t = idx - oc * 20;
        float acc = d2bs[oc];
        for (int ic = 0; ic < 32; ++ic) {
            const float* gr = &gs[wv][ic * 20];
            float a0 = (t >= 1) ? gr[t - 1] : 0.f;
            float a1 = gr[t];
            float a2 = (t + 1 < 20) ? gr[t + 1] : 0.f;
            acc += a0 * d2wt[(ic * 3 + 0) * 6 + oc]
                 + a1 * d2wt[(ic * 3 + 1) * 6 + oc]
                 + a2 * d2wt[(ic * 3 + 2) * 6 + oc];
        }
        out[(size_t)n * 120 + idx] = acc;
    }
}

// ---------------------------------------------------------------------------
extern "C" void kernel_launch(void* const* d_in, const int* in_sizes, int n_in,
                              void* d_out, int out_size, void* d_ws, size_t ws_size,
                              hipStream_t stream) {
    const float* x        = (const float*)d_in[0];
    const float* imu_mask = (const float*)d_in[1];
    const float* c1_w = (const float*)d_in[3];
    const float* c1_b = (const float*)d_in[4];
    const float* c2_w = (const float*)d_in[5];
    const float* c2_b = (const float*)d_in[6];
    const float* c3_w = (const float*)d_in[7];
    const float* c3_b = (const float*)d_in[8];
    const float* br_w = (const float*)d_in[9];
    const float* br_b = (const float*)d_in[10];
    const float* f1_w = (const float*)d_in[11];
    const float* f1_b = (const float*)d_in[12];
    const float* f2_w = (const float*)d_in[13];
    const float* f2_b = (const float*)d_in[14];
    const float* d1_w = (const float*)d_in[15];
    const float* d1_b = (const float*)d_in[16];
    const float* d2_w = (const float*)d_in[17];
    const float* d2_b = (const float*)d_in[18];
    const float* ae1_w = (const float*)d_in[19];
    const float* ae1_b = (const float*)d_in[20];
    const float* ae2_w = (const float*)d_in[21];
    const float* ae2_b = (const float*)d_in[22];
    const float* ae3_w = (const float*)d_in[23];
    const float* ae3_b = (const float*)d_in[24];
    const float* ad1_w = (const float*)d_in[25];
    const float* ad1_b = (const float*)d_in[26];
    const float* ad2_w = (const float*)d_in[27];
    const float* ad2_b = (const float*)d_in[28];

    // A from out_size: out_size = 6,176,768 + 23,040*A
    int A = (out_size - 6176768) / 23040;
    if (A < 1) A = 1;

    float* out = (float*)d_out;
    size_t o_imu_gen  = 0;
    size_t o_atom_gen = 1966080;
    size_t o_mask     = o_atom_gen + (size_t)A * 7680;
    size_t o_atoms    = o_mask + (size_t)A * 7680;
    size_t o_resh     = o_atoms + (size_t)A * 7680;
    size_t o_fin      = o_resh + 1048576;
    size_t o_fc       = o_fin + 1048576;
    size_t o_fmask    = o_fc + 1048576;
    size_t o_loss     = o_fmask + 1048576;

    // workspace layout (float units)
    float* wsf = (float*)d_ws;
    int*   wsi = (int*)d_ws;
    const size_t W_BRIDGE = 0;                       // 1,048,576
    const size_t W_FEAT   = W_BRIDGE + 1048576;      // 4,194,304
    const size_t W_SCORES = W_FEAT + 4194304;        // 16,384
    const size_t W_CUTOFF = W_SCORES + 16384;        // 64
    const size_t MW       = W_CUTOFF + 64;           // meta (int units)
    int* counts   = wsi + MW;
    int* total    = wsi + MW + 128;
    int* segs     = wsi + MW + 192;                          // BS*SEGSTRIDE
    int* rec_b    = wsi + MW + 192 + BS * SEGSTRIDE;
    int* rec_last = rec_b + RECCAP;
    int* rec_e    = rec_last + RECCAP;
    size_t HD_OFF = MW + 192 + BS * SEGSTRIDE + 3 * RECCAP;
    unsigned short* hd  = (unsigned short*)(wsf + HD_OFF);           // RECCAP*256 bf16
    unsigned short* wbT = (unsigned short*)(wsf + HD_OFF + (size_t)RECCAP * 128);  // 7680*256 bf16

    hipMemsetAsync(rec_b, 0, 3 * RECCAP * sizeof(int), stream);

    const int T = 256;
    // independent of everything downstream — run first
    dim3 gt(120, 4);
    k_wtrans<<<gt, 256, 0, stream>>>(ad2_w, wbT);
    k_encoder<<<NWIN / 4, 256, 0, stream>>>(x, c1_w, c1_b, c2_w, c2_b, c3_w, c3_b,
                                            br_w, br_b, wsf + W_BRIDGE,
                                            out + o_resh, out + o_fin);
    k_f1<<<NWIN, 256, 0, stream>>>(wsf + W_BRIDGE, f1_w, f1_b, wsf + W_FEAT);
    k_f2_loss<<<NWIN, 64, 0, stream>>>(wsf + W_FEAT, wsf + W_BRIDGE, f2_w, f2_b, imu_mask,
                                       out + o_fc, out + o_fmask, out + o_loss, wsf + W_SCORES);
    k_select<<<1, 256, 0, stream>>>(wsf + W_SCORES, wsf + W_CUTOFF);
    k_segments<<<1, 128, 0, stream>>>(out + o_loss, wsf + W_CUTOFF, segs, counts);
    k_emit<<<1, 128, 0, stream>>>(counts, segs, rec_b, rec_last, rec_e, total);
    k_gather_atoms<<<(A * 7680 + T - 1) / T, T, 0, stream>>>(rec_b, rec_last, rec_e, x,
                                                             out + o_atoms, out + o_mask, A);
    k_ae<<<A, 64, 0, stream>>>(rec_b, rec_last, rec_e, wsf + W_BRIDGE,
                               ae1_w, ae1_b, ae2_w, ae2_b, ae3_w, ae3_b,
                               ad1_w, ad1_b, hd);
    dim3 g2((A + 63) / 64, 120);
    k_ad2m<<<g2, 256, 0, stream>>>(hd, wbT, ad2_b, out + o_atom_gen, A);
    k_decoder<<<NWIN / 4, 256, 0, stream>>>(wsf + W_BRIDGE, d1_w, d1_b, d2_w, d2_b,
                                            out + o_imu_gen);
}

// Round 5
// 1072.482 us; speedup vs baseline: 1.9321x; 1.1590x over previous
//
#include <hip/hip_runtime.h>
#include <math.h>

// ---------------------------------------------------------------------------
// AtomicHAR pipeline. fp32 everywhere except the post-selection ad2 GEMM
// (bf16 MFMA — cannot affect segment selection; tolerance 9.9e-2 vs ~3e-3 err).
// bs=128 seq=128 C=6 L=20 N=16384 D=64 H=256 MAL=10 Wtot=1280
// ---------------------------------------------------------------------------

#define NWIN 16384   // bs*seq
#define SEQ  128
#define BS   128
#define KSEL 3276    // int(16384*0.2)
#define SEGSTRIDE 160    // worst-case segments per batch ~140
#define RECCAP 18432     // worst-case total segments

typedef __attribute__((ext_vector_type(8))) short short8v;
typedef __attribute__((ext_vector_type(4))) float float4v;

__device__ inline unsigned short bf16rne(float f) {
    unsigned u = __float_as_uint(f);
    unsigned r = u + 0x7FFFu + ((u >> 16) & 1u);
    return (unsigned short)(r >> 16);
}

// ---------------- fused encoder: conv1+pool, conv2+pool, conv3+pool, bridge --
__global__ __launch_bounds__(256) void k_encoder(
        const float* __restrict__ x,
        const float* __restrict__ c1w, const float* __restrict__ c1b,
        const float* __restrict__ c2w, const float* __restrict__ c2b,
        const float* __restrict__ c3w, const float* __restrict__ c3b,
        const float* __restrict__ brw, const float* __restrict__ brb,
        float* __restrict__ bridge, float* __restrict__ out_resh,
        float* __restrict__ out_fin) {
    __shared__ float c1wt[288];    // (ic*3+dk)*16 + oc
    __shared__ float c2wt[1536];   // (ic*3+dk)*32 + oc
    __shared__ float c3wt[3072];   // (ic*3+dk)*32 + oc
    __shared__ float brws[4096];   // i*64 + d
    __shared__ float c1bs[16], c2bs[32], c3bs[32], brbs[64];
    __shared__ float xs[4][128], c1s[4][160], c2s[4][160], c3s[4][64];

    int tid = threadIdx.x;
    for (int i = tid; i < 288; i += 256) {
        int oc = i / 18, r = i - oc * 18, ic = r / 3, dk = r - ic * 3;
        c1wt[(ic * 3 + dk) * 16 + oc] = c1w[i];
    }
    for (int i = tid; i < 1536; i += 256) {
        int oc = i / 48, r = i - oc * 48, ic = r / 3, dk = r - ic * 3;
        c2wt[(ic * 3 + dk) * 32 + oc] = c2w[i];
    }
    for (int i = tid; i < 3072; i += 256) {
        int oc = i / 96, r = i - oc * 96, ic = r / 3, dk = r - ic * 3;
        c3wt[(ic * 3 + dk) * 32 + oc] = c3w[i];
    }
    for (int i = tid; i < 4096; i += 256) brws[i] = brw[i];
    if (tid < 16) c1bs[tid] = c1b[tid];
    else if (tid < 48) c2bs[tid - 16] = c2b[tid - 16];
    else if (tid < 80) c3bs[tid - 48] = c3b[tid - 48];
    else if (tid < 144) brbs[tid - 80] = brb[tid - 80];

    int wv = tid >> 6, lane = tid & 63;
    int n = blockIdx.x * 4 + wv;
    const float* xr = x + (size_t)n * 120;
    if (lane < 60) ((float2*)&xs[wv][0])[lane] = ((const float2*)xr)[lane];
    __syncthreads();

    // conv1
    {
        int oc = lane >> 2, tg = lane & 3;
        float bb = c1bs[oc];
        float acc[3][2];
#pragma unroll
        for (int j = 0; j < 3; ++j) { acc[j][0] = bb; acc[j][1] = bb; }
        for (int ic = 0; ic < 6; ++ic) {
            float w0 = c1wt[(ic * 3 + 0) * 16 + oc];
            float w1 = c1wt[(ic * 3 + 1) * 16 + oc];
            float w2 = c1wt[(ic * 3 + 2) * 16 + oc];
            const float* ar = &xs[wv][ic * 20];
#pragma unroll
            for (int j = 0; j < 3; ++j) {
                int t = tg + 4 * j;
                if (t < 10) {
#pragma unroll
                    for (int q = 0; q < 2; ++q) {
                        int p = 2 * t + q;
                        float a0 = (p >= 1) ? ar[p - 1] : 0.f;
                        float a1 = ar[p];
                        float a2 = (p + 1 < 20) ? ar[p + 1] : 0.f;
                        acc[j][q] += a0 * w0 + a1 * w1 + a2 * w2;
                    }
                }
            }
        }
#pragma unroll
        for (int j = 0; j < 3; ++j) {
            int t = tg + 4 * j;
            if (t < 10) c1s[wv][oc * 10 + t] = fmaxf(fmaxf(acc[j][0], acc[j][1]), 0.f);
        }
    }
    __syncthreads();

    // conv2
    {
        int oc = lane >> 1, tg = lane & 1;
        float bb = c2bs[oc];
        float acc[3][2];
#pragma unroll
        for (int j = 0; j < 3; ++j) { acc[j][0] = bb; acc[j][1] = bb; }
        for (int ic = 0; ic < 16; ++ic) {
            float w0 = c2wt[(ic * 3 + 0) * 32 + oc];
            float w1 = c2wt[(ic * 3 + 1) * 32 + oc];
            float w2 = c2wt[(ic * 3 + 2) * 32 + oc];
            const float* ar = &c1s[wv][ic * 10];
#pragma unroll
            for (int j = 0; j < 3; ++j) {
                int t = tg + 2 * j;
                if (t < 5) {
#pragma unroll
                    for (int q = 0; q < 2; ++q) {
                        int p = 2 * t + q;
                        float a0 = (p >= 1) ? ar[p - 1] : 0.f;
                        float a1 = ar[p];
                        float a2 = (p + 1 < 10) ? ar[p + 1] : 0.f;
                        acc[j][q] += a0 * w0 + a1 * w1 + a2 * w2;
                    }
                }
            }
        }
#pragma unroll
        for (int j = 0; j < 3; ++j) {
            int t = tg + 2 * j;
            if (t < 5) c2s[wv][oc * 5 + t] = fmaxf(fmaxf(acc[j][0], acc[j][1]), 0.f);
        }
    }
    __syncthreads();

    // conv3
    {
        int oc = lane >> 1, tp = lane & 1;
        float bb = c3bs[oc];
        float acc0 = bb, acc1 = bb;
        for (int ic = 0; ic < 32; ++ic) {
            float w0 = c3wt[(ic * 3 + 0) * 32 + oc];
            float w1 = c3wt[(ic * 3 + 1) * 32 + oc];
            float w2 = c3wt[(ic * 3 + 2) * 32 + oc];
            const float* ar = &c2s[wv][ic * 5];
            {
                int p = 2 * tp;
                float a0 = (p >= 1) ? ar[p - 1] : 0.f;
                acc0 += a0 * w0 + ar[p] * w1 + ar[p + 1] * w2;
            }
            {
                int p = 2 * tp + 1;
                acc1 += ar[p - 1] * w0 + ar[p] * w1 + ((p + 1 < 5) ? ar[p + 1] : 0.f) * w2;
            }
        }
        c3s[wv][lane] = fmaxf(fmaxf(acc0, acc1), 0.f);
    }
    __syncthreads();

    // bridge
    {
        float acc = brbs[lane];
        for (int i = 0; i < 64; ++i) acc += c3s[wv][i] * brws[i * 64 + lane];
        float v = 1.f / (1.f + expf(-acc));
        size_t o = (size_t)n * 64 + lane;
        bridge[o] = v; out_resh[o] = v; out_fin[o] = v;
    }
}

__global__ void k_f1(const float* __restrict__ bridge, const float* __restrict__ w,
                     const float* __restrict__ b, float* __restrict__ feat) {
    int n = blockIdx.x, h = threadIdx.x;
    int s = n & (SEQ - 1);
    float acc = b[h];
    if (s > 0) {
        const float* br = bridge + (n - 1) * 64;
        for (int d = 0; d < 64; ++d) acc += br[d] * w[d * 256 + h];
    }
    feat[n * 256 + h] = fmaxf(acc, 0.f);
}

__global__ void k_f2_loss(const float* __restrict__ feat, const float* __restrict__ bridge,
                          const float* __restrict__ w, const float* __restrict__ b,
                          const float* __restrict__ imu_mask,
                          float* __restrict__ out_fc, float* __restrict__ out_fmask,
                          float* __restrict__ out_loss, float* __restrict__ scores) {
    int n = blockIdx.x, d = threadIdx.x;
    const float* fr = feat + n * 256;
    float acc = b[d];
    for (int h = 0; h < 256; ++h) acc += fr[h] * w[h * 64 + d];
    out_fc[n * 64 + d] = acc;
    int s = n & (SEQ - 1);
    float mval = (s == 0) ? 0.f : imu_mask[(size_t)n * 120];
    out_fmask[n * 64 + d] = mval;
    float diff = (acc - bridge[n * 64 + d]) * mval;
    float sq = diff * diff;
#pragma unroll
    for (int off = 32; off; off >>= 1) sq += __shfl_down(sq, off);
    if (d == 0) {
        float loss = sq * (1.f / 64.f);
        out_loss[n] = loss;
        scores[n] = loss * mval;
    }
}

// exact k-th largest via radix select on float bits (scores >= 0). 1 block x 256.
__global__ void k_select(const float* __restrict__ scores, float* __restrict__ cutoff) {
    __shared__ unsigned hist[256];
    __shared__ unsigned sh_prefix;
    __shared__ int sh_k;
    int tid = threadIdx.x;
    if (tid == 0) { sh_prefix = 0u; sh_k = KSEL; }
    __syncthreads();
    for (int shift = 24; shift >= 0; shift -= 8) {
        hist[tid] = 0u;
        __syncthreads();
        unsigned prefix = sh_prefix;
        unsigned pmask = (shift == 24) ? 0u : (0xFFFFFFFFu << (shift + 8));
        for (int i = tid; i < NWIN; i += 256) {
            unsigned u = __float_as_uint(scores[i]);
            if ((u & pmask) == prefix) atomicAdd(&hist[(u >> shift) & 255u], 1u);
        }
        __syncthreads();
        if (tid == 0) {
            int kk = sh_k;
            for (int bin = 255; bin >= 0; --bin) {
                int c = (int)hist[bin];
                if (kk <= c) { sh_prefix = prefix | ((unsigned)bin << shift); sh_k = kk; break; }
                kk -= c;
            }
        }
        __syncthreads();
    }
    if (tid == 0) *cutoff = __uint_as_float(sh_prefix);
}

// per-batch segmentation with gap-fill. 1 block x 128 (thread per batch).
__global__ void k_segments(const float* __restrict__ loss, const float* __restrict__ cutoff_p,
                           int* __restrict__ segs, int* __restrict__ counts) {
    int b = threadIdx.x;
    if (b >= BS) return;
    float cutoff = *cutoff_p;
    int* my = segs + b * SEGSTRIDE;
    int cnt = 0, prev = 0;
    bool has = false;
    for (int s = 0; s < SEQ; ++s) {
        if (loss[b * SEQ + s] > cutoff) {
            if (has) {
                if (s - prev > 10) {
                    my[cnt++] = prev;
                    int cur = prev;
                    while (cur < s) {
                        cur += 10;
                        if (cur >= s) break;
                        my[cnt++] = cur;
                    }
                } else {
                    my[cnt++] = prev;
                }
            }
            has = true; prev = s;
        }
    }
    if (has) my[cnt++] = prev;
    counts[b] = cnt;
}

// prefix-scan counts, emit (b,last,e) records. 1 block x 128.
__global__ void k_emit(const int* __restrict__ counts, const int* __restrict__ segs,
                       int* __restrict__ rec_b, int* __restrict__ rec_last,
                       int* __restrict__ rec_e, int* __restrict__ total_out) {
    __shared__ int offs[BS + 1];
    int tid = threadIdx.x;
    if (tid == 0) {
        int acc = 0;
        for (int b = 0; b < BS; ++b) { offs[b] = acc; acc += counts[b]; }
        offs[BS] = acc;
        *total_out = acc;
        if (acc == 0) { rec_b[0] = 0; rec_last[0] = 0; rec_e[0] = 0; }  // fallback dummy
    }
    __syncthreads();
    int b = tid;
    int o = offs[b], c = counts[b];
    for (int j = 0; j < c; ++j) {
        int idx = o + j;
        if (idx >= RECCAP) break;
        rec_b[idx] = b;
        rec_last[idx] = (j > 0) ? segs[b * SEGSTRIDE + j - 1] : 0;
        rec_e[idx] = segs[b * SEGSTRIDE + j];
    }
}

// imu_atoms + mask: (A, 6, 1280)
__global__ void k_gather_atoms(const int* __restrict__ rec_b, const int* __restrict__ rec_last,
                               const int* __restrict__ rec_e, const float* __restrict__ x,
                               float* __restrict__ out_atoms, float* __restrict__ out_mask, int A) {
    int gid = blockIdx.x * blockDim.x + threadIdx.x;
    if (gid >= A * 7680) return;
    int a = gid / 7680, rem = gid % 7680, c = rem / 1280, wcol = rem % 1280;
    int b = rec_b[a], last = rec_last[a], e = rec_e[a];
    int W = (e - last) * 20;
    int sc = wcol - (1280 - W);
    float v = 0.f, m = 0.f;
    if (sc >= 0 && sc < W) {
        int t = sc / 20, l = sc % 20;
        v = x[((b * SEQ + last + t) * 6 + c) * 20 + l];
        m = 1.f;
    }
    out_atoms[gid] = v;
    out_mask[gid] = m;
}

// ---------------- autoencoder, batched: 8 segments/block, 256 threads -------
// LDS-staged transposed weights; ae1 p-loop register-hoisted; ad1 joint.
__global__ __launch_bounds__(256) void k_ae2(
        const int* __restrict__ rec_b, const int* __restrict__ rec_last,
        const int* __restrict__ rec_e, const float* __restrict__ bridge,
        const float* __restrict__ ae1w, const float* __restrict__ ae1b,
        const float* __restrict__ ae2w, const float* __restrict__ ae2b,
        const float* __restrict__ ae3w, const float* __restrict__ ae3b,
        const float* __restrict__ ad1w, const float* __restrict__ ad1b,
        unsigned short* __restrict__ hd, int A) {
    __shared__ float ae1wt[6144];   // (ic*3+dk)*32 + o   (o<32, ic<64)
    __shared__ float ae2wt[1536];   // (ic*3+dk)*16 + c   (c<16, ic<32)
    __shared__ float ae3ws[2560];   // i*32 + o
    __shared__ float ae1bs[32], ae2bs[16], ae3bs[32];
    __shared__ float af_s[8][640];  // [seg][ic*10+r]
    __shared__ float c1p[8][160];   // pooled+relu ae1 out [seg][o*5+t]
    __shared__ float h2s[8][80];    // [seg][c*5+t]
    __shared__ float embs[32][8];   // [o][seg]

    int tid = threadIdx.x;
    int a0 = blockIdx.x * 8;

    // ---- stage weights (transposed) ----
    for (int i = tid; i < 6144; i += 256) {
        int o = i / 192, r = i - o * 192, ic = r / 3, dk = r - ic * 3;
        ae1wt[(ic * 3 + dk) * 32 + o] = ae1w[i];
    }
    for (int i = tid; i < 1536; i += 256) {
        int c = i / 96, r = i - c * 96, ic = r / 3, dk = r - ic * 3;
        ae2wt[(ic * 3 + dk) * 16 + c] = ae2w[i];
    }
    for (int i = tid; i < 2560; i += 256) ae3ws[i] = ae3w[i];
    if (tid < 32) ae1bs[tid] = ae1b[tid];
    else if (tid < 48) ae2bs[tid - 32] = ae2b[tid - 32];
    else if (tid < 80) ae3bs[tid - 48] = ae3b[tid - 48];

    // ---- gather af from bridge (each wave: its 2 segments) ----
    int wv = tid >> 6, lane = tid & 63;
#pragma unroll
    for (int sg = 0; sg < 2; ++sg) {
        int seg = wv * 2 + sg;
        int ac = a0 + seg; if (ac > A - 1) ac = A - 1;
        int b = rec_b[ac], last = rec_last[ac], e = rec_e[ac];
#pragma unroll
        for (int r = 0; r < 10; ++r) {
            int src = e - 10 + r;
            float v = (src >= last) ? bridge[(size_t)(b * SEQ + src) * 64 + lane] : 0.f;
            af_s[seg][lane * 10 + r] = v;
        }
    }
    __syncthreads();

    // ---- ae1 conv + relu + pool: seg = wv*2 + (lane>>5), o = lane&31 ----
    {
        int seg = wv * 2 + (lane >> 5);
        int o = lane & 31;
        const float* afl = af_s[seg];
        float bb = ae1bs[o];
        float acc[10];
#pragma unroll
        for (int p = 0; p < 10; ++p) acc[p] = bb;
        for (int ic = 0; ic < 64; ++ic) {
            float av[10];
#pragma unroll
            for (int r = 0; r < 10; ++r) av[r] = afl[ic * 10 + r];  // broadcast
            float w0 = ae1wt[(ic * 3 + 0) * 32 + o];
            float w1 = ae1wt[(ic * 3 + 1) * 32 + o];
            float w2 = ae1wt[(ic * 3 + 2) * 32 + o];
            acc[0] += av[0] * w1 + av[1] * w2;
#pragma unroll
            for (int p = 1; p < 9; ++p)
                acc[p] += av[p - 1] * w0 + av[p] * w1 + av[p + 1] * w2;
            acc[9] += av[8] * w0 + av[9] * w1;
        }
#pragma unroll
        for (int t = 0; t < 5; ++t)
            c1p[seg][o * 5 + t] = fmaxf(fmaxf(acc[2 * t], acc[2 * t + 1]), 0.f);
    }
    __syncthreads();

    // ---- ae2 conv + relu: seg = wv*2+(lane>>5); c = (lane&31)>>1, th = lane&1 ----
    {
        int seg = wv * 2 + (lane >> 5);
        int c = (lane & 31) >> 1, th = lane & 1;
        const float* cp = c1p[seg];
        float bb = ae2bs[c];
        float acc2[3] = {bb, bb, bb};
        for (int ic = 0; ic < 32; ++ic) {
            float m[5];
#pragma unroll
            for (int t = 0; t < 5; ++t) m[t] = cp[ic * 5 + t];  // broadcast
            float w0 = ae2wt[(ic * 3 + 0) * 16 + c];
            float w1 = ae2wt[(ic * 3 + 1) * 16 + c];
            float w2 = ae2wt[(ic * 3 + 2) * 16 + c];
#pragma unroll
            for (int j = 0; j < 3; ++j) {
                int t = th + 2 * j;
                if (t < 5) {
                    float am1 = (t > 0) ? m[t - 1] : 0.f;
                    float ap1 = (t < 4) ? m[t + 1] : 0.f;
                    acc2[j] += am1 * w0 + m[t] * w1 + ap1 * w2;
                }
            }
        }
#pragma unroll
        for (int j = 0; j < 3; ++j) {
            int t = th + 2 * j;
            if (t < 5) h2s[seg][c * 5 + t] = fmaxf(acc2[j], 0.f);
        }
    }
    __syncthreads();

    // ---- ae3: emb(32) per seg: seg = wv*2+(lane>>5), o = lane&31 ----
    {
        int seg = wv * 2 + (lane >> 5);
        int o = lane & 31;
        float acc = ae3bs[o];
        const float* hh = h2s[seg];
        for (int i = 0; i < 80; ++i) acc += hh[i] * ae3ws[i * 32 + o];
        embs[o][seg] = acc;   // no relu on emb
    }
    __syncthreads();

    // ---- ad1 joint: thread tid owns output column idx for ALL 8 segs ----
    {
        int idx = tid;
        float bb = ad1b[idx];
        float acc[8];
#pragma unroll
        for (int s = 0; s < 8; ++s) acc[s] = bb;
        for (int o = 0; o < 32; ++o) {
            float wq = ad1w[o * 256 + idx];   // coalesced, reused 8x
#pragma unroll
            for (int s = 0; s < 8; ++s) acc[s] += embs[o][s] * wq;
        }
#pragma unroll
        for (int s = 0; s < 8; ++s) {
            int a = a0 + s;
            if (a < A) hd[(size_t)a * 256 + idx] = bf16rne(fmaxf(acc[s], 0.f));
        }
    }
}

// transpose + bf16-cast ad2_w (256 x 7680, row-major) -> wbT (7680 x 256, n-major)
__global__ __launch_bounds__(256) void k_wtrans(const float* __restrict__ w,
                                                unsigned short* __restrict__ wbT) {
    __shared__ float tile[64][65];
    int n0 = blockIdx.x * 64, k0 = blockIdx.y * 64;
    int tid = threadIdx.x;
    int c = tid & 63;
    for (int r = tid >> 6; r < 64; r += 4)
        tile[r][c] = w[(size_t)(k0 + r) * 7680 + n0 + c];
    __syncthreads();
    int n = tid >> 4, kq = (tid & 15) * 4;
    for (int nn = n; nn < 64; nn += 16) {
        unsigned p0 = (unsigned)bf16rne(tile[kq + 0][nn]) |
                      ((unsigned)bf16rne(tile[kq + 1][nn]) << 16);
        unsigned p1 = (unsigned)bf16rne(tile[kq + 2][nn]) |
                      ((unsigned)bf16rne(tile[kq + 3][nn]) << 16);
        unsigned* dst = (unsigned*)&wbT[(size_t)(n0 + nn) * 256 + k0 + kq];
        dst[0] = p0; dst[1] = p1;
    }
}

// atom_gen = hd(A,256)bf16 @ wbT^T + ad2_b via MFMA 16x16x32 bf16.
// Block: 256 thr = 4 waves; tile 64m x 64n; K=256 fully in LDS.
#define LSTR 264   // shorts per LDS row (256 + 8 pad)
__global__ __launch_bounds__(256) void k_ad2m(const unsigned short* __restrict__ hdb,
                                              const unsigned short* __restrict__ wbT,
                                              const float* __restrict__ bias,
                                              float* __restrict__ out, int A) {
    __shared__ unsigned short hs[64 * LSTR];
    __shared__ unsigned short wt[64 * LSTR];
    int tid = threadIdx.x;
    int m0 = blockIdx.x * 64;
    int n0 = blockIdx.y * 64;

    const unsigned* hdu = (const unsigned*)hdb;
    const unsigned* wtu = (const unsigned*)wbT;
#pragma unroll 4
    for (int i = 0; i < 32; ++i) {
        int flat = tid + 256 * i;          // 0..8191
        int row = flat >> 7, d = flat & 127;
        unsigned hv = 0;
        if (m0 + row < A) hv = hdu[(size_t)(m0 + row) * 128 + d];
        *(unsigned*)&hs[row * LSTR + d * 2] = hv;
        *(unsigned*)&wt[row * LSTR + d * 2] = wtu[(size_t)(n0 + row) * 128 + d];
    }
    __syncthreads();

    int wv = tid >> 6, lane = tid & 63;
    int rc = lane & 15;
    int koff = (lane >> 4) * 8;
    float4v acc[4];
#pragma unroll
    for (int i = 0; i < 4; ++i) acc[i] = (float4v){0.f, 0.f, 0.f, 0.f};

    const short* ha = (const short*)&hs[(wv * 16 + rc) * LSTR + koff];
#pragma unroll
    for (int s = 0; s < 8; ++s) {
        short8v a = *(const short8v*)(ha + s * 32);
#pragma unroll
        for (int nt = 0; nt < 4; ++nt) {
            short8v b = *(const short8v*)((const short*)&wt[(nt * 16 + rc) * LSTR + s * 32 + koff]);
            acc[nt] = __builtin_amdgcn_mfma_f32_16x16x32_bf16(a, b, acc[nt], 0, 0, 0);
        }
    }

    int quad = lane >> 4;
#pragma unroll
    for (int nt = 0; nt < 4; ++nt) {
        int n = n0 + nt * 16 + rc;
        float bb = bias[n];
#pragma unroll
        for (int r = 0; r < 4; ++r) {
            int m = m0 + wv * 16 + quad * 4 + r;
            if (m < A) out[(size_t)m * 7680 + n] = acc[nt][r] + bb;
        }
    }
}

// decoder: 4 waves/block, one n per wave; weights staged transposed in LDS.
__global__ __launch_bounds__(256) void k_decoder(const float* __restrict__ bridge,
                          const float* __restrict__ d1w, const float* __restrict__ d1b,
                          const float* __restrict__ d2w, const float* __restrict__ d2b,
                          float* __restrict__ out) {
    __shared__ float d1wt[16 * 5 * 33];   // (c*5+kk)*33 + o
    __shared__ float d2wt[576];           // (ic*3+dk)*6 + oc
    __shared__ float d1bs[32], d2bs[8];
    __shared__ float brs[4][64];
    __shared__ float gs[4][640];
    int tid = threadIdx.x;
    for (int i = tid; i < 2560; i += 256) {
        int c = i / 160, r = i - c * 160, o = r / 5, kk = r - o * 5;
        d1wt[(c * 5 + kk) * 33 + o] = d1w[i];
    }
    for (int i = tid; i < 576; i += 256) {
        int oc = i / 96, r = i - oc * 96, ic = r / 3, dk = r - ic * 3;
        d2wt[(ic * 3 + dk) * 6 + oc] = d2w[i];
    }
    if (tid < 32) d1bs[tid] = d1b[tid];
    else if (tid < 38) d2bs[tid - 32] = d2b[tid - 32];
    int wv = tid >> 6, lane = tid & 63;
    int n = blockIdx.x * 4 + wv;
    brs[wv][lane] = bridge[(size_t)n * 64 + lane];
    __syncthreads();
    for (int idx = lane; idx < 640; idx += 64) {
        int o = idx / 20, p = idx - o * 20, i = p / 5, kk = p - i * 5;
        float acc = d1bs[o];
#pragma unroll
        for (int c = 0; c < 16; ++c) acc += brs[wv][c * 4 + i] * d1wt[(c * 5 + kk) * 33 + o];
        gs[wv][idx] = fmaxf(acc, 0.f);
    }
    __syncthreads();
    for (int idx = lane; idx < 120; idx += 64) {
        int oc = idx / 20, t = idx - oc * 20;
        float acc = d2bs[oc];
        for (int ic = 0; ic < 32; ++ic) {
            const float* gr = &gs[wv][ic * 20];
            float a0 = (t >= 1) ? gr[t - 1] : 0.f;
            float a1 = gr[t];
            float a2 = (t + 1 < 20) ? gr[t + 1] : 0.f;
            acc += a0 * d2wt[(ic * 3 + 0) * 6 + oc]
                 + a1 * d2wt[(ic * 3 + 1) * 6 + oc]
                 + a2 * d2wt[(ic * 3 + 2) * 6 + oc];
        }
        out[(size_t)n * 120 + idx] = acc;
    }
}

// ---------------------------------------------------------------------------
extern "C" void kernel_launch(void* const* d_in, const int* in_sizes, int n_in,
                              void* d_out, int out_size, void* d_ws, size_t ws_size,
                              hipStream_t stream) {
    const float* x        = (const float*)d_in[0];
    const float* imu_mask = (const float*)d_in[1];
    const float* c1_w = (const float*)d_in[3];
    const float* c1_b = (const float*)d_in[4];
    const float* c2_w = (const float*)d_in[5];
    const float* c2_b = (const float*)d_in[6];
    const float* c3_w = (const float*)d_in[7];
    const float* c3_b = (const float*)d_in[8];
    const float* br_w = (const float*)d_in[9];
    const float* br_b = (const float*)d_in[10];
    const float* f1_w = (const float*)d_in[11];
    const float* f1_b = (const float*)d_in[12];
    const float* f2_w = (const float*)d_in[13];
    const float* f2_b = (const float*)d_in[14];
    const float* d1_w = (const float*)d_in[15];
    const float* d1_b = (const float*)d_in[16];
    const float* d2_w = (const float*)d_in[17];
    const float* d2_b = (const float*)d_in[18];
    const float* ae1_w = (const float*)d_in[19];
    const float* ae1_b = (const float*)d_in[20];
    const float* ae2_w = (const float*)d_in[21];
    const float* ae2_b = (const float*)d_in[22];
    const float* ae3_w = (const float*)d_in[23];
    const float* ae3_b = (const float*)d_in[24];
    const float* ad1_w = (const float*)d_in[25];
    const float* ad1_b = (const float*)d_in[26];
    const float* ad2_w = (const float*)d_in[27];
    const float* ad2_b = (const float*)d_in[28];

    // A from out_size: out_size = 6,176,768 + 23,040*A
    int A = (out_size - 6176768) / 23040;
    if (A < 1) A = 1;

    float* out = (float*)d_out;
    size_t o_imu_gen  = 0;
    size_t o_atom_gen = 1966080;
    size_t o_mask     = o_atom_gen + (size_t)A * 7680;
    size_t o_atoms    = o_mask + (size_t)A * 7680;
    size_t o_resh     = o_atoms + (size_t)A * 7680;
    size_t o_fin      = o_resh + 1048576;
    size_t o_fc       = o_fin + 1048576;
    size_t o_fmask    = o_fc + 1048576;
    size_t o_loss     = o_fmask + 1048576;

    // workspace layout (float units)
    float* wsf = (float*)d_ws;
    int*   wsi = (int*)d_ws;
    const size_t W_BRIDGE = 0;                       // 1,048,576
    const size_t W_FEAT   = W_BRIDGE + 1048576;      // 4,194,304
    const size_t W_SCORES = W_FEAT + 4194304;        // 16,384
    const size_t W_CUTOFF = W_SCORES + 16384;        // 64
    const size_t MW       = W_CUTOFF + 64;           // meta (int units)
    int* counts   = wsi + MW;
    int* total    = wsi + MW + 128;
    int* segs     = wsi + MW + 192;                          // BS*SEGSTRIDE
    int* rec_b    = wsi + MW + 192 + BS * SEGSTRIDE;
    int* rec_last = rec_b + RECCAP;
    int* rec_e    = rec_last + RECCAP;
    size_t HD_OFF = MW + 192 + BS * SEGSTRIDE + 3 * RECCAP;
    unsigned short* hd  = (unsigned short*)(wsf + HD_OFF);           // RECCAP*256 bf16
    unsigned short* wbT = (unsigned short*)(wsf + HD_OFF + (size_t)RECCAP * 128);  // 7680*256 bf16

    hipMemsetAsync(rec_b, 0, 3 * RECCAP * sizeof(int), stream);

    const int T = 256;
    // independent of everything downstream — run first
    dim3 gt(120, 4);
    k_wtrans<<<gt, 256, 0, stream>>>(ad2_w, wbT);
    k_encoder<<<NWIN / 4, 256, 0, stream>>>(x, c1_w, c1_b, c2_w, c2_b, c3_w, c3_b,
                                            br_w, br_b, wsf + W_BRIDGE,
                                            out + o_resh, out + o_fin);
    k_f1<<<NWIN, 256, 0, stream>>>(wsf + W_BRIDGE, f1_w, f1_b, wsf + W_FEAT);
    k_f2_loss<<<NWIN, 64, 0, stream>>>(wsf + W_FEAT, wsf + W_BRIDGE, f2_w, f2_b, imu_mask,
                                       out + o_fc, out + o_fmask, out + o_loss, wsf + W_SCORES);
    k_select<<<1, 256, 0, stream>>>(wsf + W_SCORES, wsf + W_CUTOFF);
    k_segments<<<1, 128, 0, stream>>>(out + o_loss, wsf + W_CUTOFF, segs, counts);
    k_emit<<<1, 128, 0, stream>>>(counts, segs, rec_b, rec_last, rec_e, total);
    k_gather_atoms<<<(A * 7680 + T - 1) / T, T, 0, stream>>>(rec_b, rec_last, rec_e, x,
                                                             out + o_atoms, out + o_mask, A);
    k_ae2<<<(A + 7) / 8, 256, 0, stream>>>(rec_b, rec_last, rec_e, wsf + W_BRIDGE,
                                           ae1_w, ae1_b, ae2_w, ae2_b, ae3_w, ae3_b,
                                           ad1_w, ad1_b, hd, A);
    dim3 g2((A + 63) / 64, 120);
    k_ad2m<<<g2, 256, 0, stream>>>(hd, wbT, ad2_b, out + o_atom_gen, A);
    k_decoder<<<NWIN / 4, 256, 0, stream>>>(wsf + W_BRIDGE, d1_w, d1_b, d2_w, d2_b,
                                            out + o_imu_gen);
}